// Round 1
// baseline (18095.450 us; speedup 1.0000x reference)
//
#include <hip/hip_runtime.h>
#include <math.h>

// NMT seq2seq fwd: E=512, HE=HD=1024, V=32000, B=64, S=48, T=48.
// Round 1: correctness-first fp32. All GEMMs LDS-tiled NT (A[M,K]·B[N,K]^T).
// Sequential LSTM steps use split-K partial GEMMs (deterministic, no atomics).
// Vocab projection fuses log-sum-exp partials + gold gather (no 385MB logits).
// Workspace requirement: ~251 MB (offsets below).

#define S_    48
#define B_    64
#define E_    512
#define H_    1024
#define H4_   4096
#define V_    32000
#define T1_   47
#define NROW_ 3008   // T1_*B_
#define NTV_  250    // V_/128

__device__ __forceinline__ float sigm(float x){ return 1.f/(1.f+expf(-x)); }

// ---------------- generic NT GEMM: C[M,N] = A[M,K](lda) * B[N,K](ldb)^T + bias ----------
template<int BM,int BN,int TM,int TN>
__global__ __launch_bounds__(256)
void gemm_nt(int M, int K,
             const float* __restrict__ A, int lda,
             const float* __restrict__ B, int ldb,
             float* __restrict__ C, int ldc,
             const float* __restrict__ bias)
{
  constexpr int BK=16;
  __shared__ float As[BK][BM+4];
  __shared__ float Bs[BK][BN+4];
  const int tid=threadIdx.x;
  constexpr int TX=BN/TN;
  const int tx=tid%TX, ty=tid/TX;
  const int m0=blockIdx.x*BM, n0=blockIdx.y*BN;
  float acc[TM][TN];
#pragma unroll
  for(int i=0;i<TM;i++)
#pragma unroll
    for(int j=0;j<TN;j++) acc[i][j]=0.f;

  for(int k0=0;k0<K;k0+=BK){
    for(int i=tid;i<BM*4;i+=256){         // BM*BK/4 float4 loads
      int r=i>>2, c=(i&3)*4;
      float4 v=make_float4(0.f,0.f,0.f,0.f);
      if(m0+r<M) v=*(const float4*)(A+(size_t)(m0+r)*lda+k0+c);
      As[c+0][r]=v.x; As[c+1][r]=v.y; As[c+2][r]=v.z; As[c+3][r]=v.w;
    }
    for(int i=tid;i<BN*4;i+=256){
      int r=i>>2, c=(i&3)*4;
      float4 v=*(const float4*)(B+(size_t)(n0+r)*ldb+k0+c);
      Bs[c+0][r]=v.x; Bs[c+1][r]=v.y; Bs[c+2][r]=v.z; Bs[c+3][r]=v.w;
    }
    __syncthreads();
#pragma unroll
    for(int k=0;k<BK;k++){
      float a[TM], bb[TN];
#pragma unroll
      for(int i=0;i<TM;i++) a[i]=As[k][ty*TM+i];
#pragma unroll
      for(int j=0;j<TN;j++) bb[j]=Bs[k][tx*TN+j];
#pragma unroll
      for(int i=0;i<TM;i++)
#pragma unroll
        for(int j=0;j<TN;j++) acc[i][j]+=a[i]*bb[j];
    }
    __syncthreads();
  }
#pragma unroll
  for(int i=0;i<TM;i++){
    int r=m0+ty*TM+i;
    if(r>=M) continue;
#pragma unroll
    for(int j=0;j<TN;j++){
      int c=n0+tx*TN+j;
      float v=acc[i][j];
      if(bias) v+=bias[c];
      C[(size_t)r*ldc+c]=v;
    }
  }
}

// ------- small-M (=64) split-K partial GEMM; grid(ntiles, kchunks, dirs) -----------
// P[(dir*KC+kc)][64][N] = A_dir[64, kc-chunk] * B_dir[ntile, kc-chunk]^T
__global__ __launch_bounds__(256)
void msmall_part(const float* __restrict__ A0, const float* __restrict__ A1, int lda,
                 const float* __restrict__ B0, const float* __restrict__ B1, int ldb,
                 int N, int kchunk, float* __restrict__ P)
{
  const int dir=blockIdx.z;
  const float* A=(dir?A1:A0)+(size_t)blockIdx.y*kchunk;
  const float* B=(dir?B1:B0)+(size_t)blockIdx.y*kchunk+(size_t)blockIdx.x*64*ldb;
  float* Po=P+((size_t)(dir*gridDim.y+blockIdx.y)*64*N)+blockIdx.x*64;
  __shared__ float As[16][68];
  __shared__ float Bs[16][68];
  const int tid=threadIdx.x, tx=tid&15, ty=tid>>4;
  float acc[4][4]={};
  for(int k0=0;k0<kchunk;k0+=16){
    {
      int r=tid>>2, c=(tid&3)*4;
      float4 v=*(const float4*)(A+(size_t)r*lda+k0+c);
      As[c+0][r]=v.x; As[c+1][r]=v.y; As[c+2][r]=v.z; As[c+3][r]=v.w;
      float4 w=*(const float4*)(B+(size_t)r*ldb+k0+c);
      Bs[c+0][r]=w.x; Bs[c+1][r]=w.y; Bs[c+2][r]=w.z; Bs[c+3][r]=w.w;
    }
    __syncthreads();
#pragma unroll
    for(int k=0;k<16;k++){
      float a[4],bb[4];
#pragma unroll
      for(int i=0;i<4;i++) a[i]=As[k][ty*4+i];
#pragma unroll
      for(int j=0;j<4;j++) bb[j]=Bs[k][tx*4+j];
#pragma unroll
      for(int i=0;i<4;i++)
#pragma unroll
        for(int j=0;j<4;j++) acc[i][j]+=a[i]*bb[j];
    }
    __syncthreads();
  }
#pragma unroll
  for(int i=0;i<4;i++)
#pragma unroll
    for(int j=0;j<4;j++)
      Po[(size_t)(ty*4+i)*N + tx*4+j]=acc[i][j];
}

// -------------------- embeddings: X, Xrev (reversed valid prefix), Y ---------------
__global__ void embed_all(const int* __restrict__ src, const int* __restrict__ tgt,
                          const int* __restrict__ lens,
                          const float* __restrict__ se, const float* __restrict__ te,
                          float* __restrict__ X, float* __restrict__ Xr, float* __restrict__ Y)
{
  int bi=blockIdx.x, tid=threadIdx.x;
  if(bi<3072){
    int s=bi>>6, b=bi&63;
    int tok=src[s*64+b];
    ((float4*)(X+(size_t)bi*E_))[tid]=((const float4*)(se+(size_t)tok*E_))[tid];
  } else if(bi<6144){
    int r=bi-3072, t=r>>6, b=r&63;
    int L=lens[b]; int ts=(t<L)? L-1-t : t;
    int tok=src[ts*64+b];
    ((float4*)(Xr+(size_t)r*E_))[tid]=((const float4*)(se+(size_t)tok*E_))[tid];
  } else {
    int r=bi-6144, t=r>>6, b=r&63;
    int tok=tgt[t*64+b];
    ((float4*)(Y+(size_t)r*E_))[tid]=((const float4*)(te+(size_t)tok*E_))[tid];
  }
}

// ------------- encoder step epilogue: sum partials, gates, mask, outputs ----------
__global__ __launch_bounds__(256)
void enc_gates(const float* __restrict__ xpf_t, const float* __restrict__ xpb_t,
               const float* __restrict__ part, const int* __restrict__ lens,
               const float* __restrict__ hf_cur, float* __restrict__ hf_nxt, float* __restrict__ cf,
               const float* __restrict__ hb_cur, float* __restrict__ hb_nxt, float* __restrict__ cb,
               float* __restrict__ fwd_t, float* __restrict__ bwdr_t, int t)
{
  const int dir=blockIdx.y;
  const int idx=blockIdx.x*256+threadIdx.x;     // b*1024+hj
  const int b=idx>>10, hj=idx&1023;
  const float* xp = dir? xpb_t : xpf_t;
  const float* P  = part + (size_t)dir*8*64*H4_;
  float g[4];
#pragma unroll
  for(int gi=0;gi<4;gi++){
    int col=hj+gi*1024;
    float v=xp[(size_t)b*H4_+col];
#pragma unroll
    for(int kc=0;kc<8;kc++) v+=P[(size_t)kc*64*H4_+(size_t)b*H4_+col];
    g[gi]=v;
  }
  const float* hc = dir? hb_cur: hf_cur;
  float* hn = dir? hb_nxt: hf_nxt;
  float* cc = dir? cb: cf;
  float c_old=cc[idx];
  float cn=sigm(g[1])*c_old+sigm(g[0])*tanhf(g[2]);
  float hv=sigm(g[3])*tanhf(cn);
  bool m = t<lens[b];
  cc[idx]= m? cn : c_old;
  hn[idx]= m? hv : hc[idx];
  float* ot = dir? bwdr_t : fwd_t;
  ot[idx]= m? hv : 0.f;
}

// --- build enc_hiddens (B,S,2HE) with bwd un-reversal; concat final h/c states ---
__global__ void gather_concat(const float* __restrict__ fwd, const float* __restrict__ bwdR,
                              const int* __restrict__ lens,
                              const float* __restrict__ hfF, const float* __restrict__ hbF,
                              const float* __restrict__ cfF, const float* __restrict__ cbF,
                              float* __restrict__ encH, float* __restrict__ hcat, float* __restrict__ ccat)
{
  int bi=blockIdx.x, tid=threadIdx.x;
  if(bi<3072){
    int b=bi/48, s=bi%48;
    float4* dst=(float4*)(encH+(size_t)bi*2048);
    const float4* f=(const float4*)(fwd+(size_t)(s*64+b)*H_);
    int L=lens[b]; int sr=(s<L)? L-1-s : s;
    const float4* w=(const float4*)(bwdR+(size_t)(sr*64+b)*H_);
    dst[tid]=f[tid]; dst[256+tid]=w[tid];
  } else if(bi<3136){
    int b=bi-3072;
    ((float4*)(hcat+(size_t)b*2048))[tid]      =((const float4*)(hfF+(size_t)b*H_))[tid];
    ((float4*)(hcat+(size_t)b*2048+1024))[tid] =((const float4*)(hbF+(size_t)b*H_))[tid];
  } else {
    int b=bi-3136;
    ((float4*)(ccat+(size_t)b*2048))[tid]      =((const float4*)(cfF+(size_t)b*H_))[tid];
    ((float4*)(ccat+(size_t)b*2048+1024))[tid] =((const float4*)(cbF+(size_t)b*H_))[tid];
  }
}

// ------------- decoder step epilogue (h,c NOT carried; c0 constant) ---------------
__global__ __launch_bounds__(256)
void dec_gates(const float* __restrict__ yp_t, const float* __restrict__ whhc,
               const float* __restrict__ part, const float* __restrict__ dc0,
               float* __restrict__ h_t, float* __restrict__ cat)
{
  const int idx=blockIdx.x*256+threadIdx.x;
  const int b=idx>>10, hj=idx&1023;
  float g[4];
#pragma unroll
  for(int gi=0;gi<4;gi++){
    int col=hj+gi*1024;
    float v=yp_t[(size_t)b*H4_+col]+whhc[(size_t)b*H4_+col];
#pragma unroll
    for(int kc=0;kc<8;kc++) v+=part[(size_t)kc*64*H4_+(size_t)b*H4_+col];
    g[gi]=v;
  }
  float cn=sigm(g[1])*dc0[idx]+sigm(g[0])*tanhf(g[2]);
  float hv=sigm(g[3])*tanhf(cn);
  h_t[idx]=hv;
  cat[(size_t)b*3072+2048+hj]=hv;    // h part of [a | h] for O projection
}

// ---- attention: e = enc_proj·h, masked softmax over S, a = alpha·enc_hiddens ----
__global__ __launch_bounds__(256)
void attn_kernel(const float* __restrict__ h_t, const float* __restrict__ encP,
                 const float* __restrict__ encH, const int* __restrict__ lens,
                 float* __restrict__ cat)
{
  __shared__ float hs[H_];
  __shared__ float es[S_];
  __shared__ float al[S_];
  const int b=blockIdx.x, tid=threadIdx.x;
  ((float4*)hs)[tid]=((const float4*)(h_t+(size_t)b*H_))[tid];
  __syncthreads();
  const int wave=tid>>6, lane=tid&63;
  for(int s=wave;s<S_;s+=4){
    const float* ep=encP+(size_t)(b*S_+s)*H_;
    float sum=0.f;
    for(int k=lane;k<H_;k+=64) sum+=ep[k]*hs[k];
    for(int o=32;o>0;o>>=1) sum+=__shfl_xor(sum,o,64);
    if(lane==0) es[s]=sum;
  }
  __syncthreads();
  if(tid<64){
    int L=lens[b];
    float e=(tid<S_ && tid<L)? es[tid] : -INFINITY;
    float m=e;
    for(int o=32;o>0;o>>=1) m=fmaxf(m,__shfl_xor(m,o,64));
    float p=(tid<S_)? expf(e-m):0.f;
    float sm=p;
    for(int o=32;o>0;o>>=1) sm+=__shfl_xor(sm,o,64);
    if(tid<S_) al[tid]=p/sm;
  }
  __syncthreads();
  for(int d=tid;d<2048;d+=256){
    float a=0.f;
    for(int s=0;s<S_;s++) a+=al[s]*encH[(size_t)(b*S_+s)*2048+d];
    cat[(size_t)b*3072+d]=a;
  }
}

// -------- finalize O = tanh(sum partials); feeds o_prev and combined[t] ----------
__global__ void ofin(const float* __restrict__ part, float* __restrict__ o_prev,
                     float* __restrict__ comb_t)
{
  int idx=blockIdx.x*256+threadIdx.x;   // 64*1024
  float v=0.f;
#pragma unroll
  for(int kc=0;kc<4;kc++) v+=part[(size_t)kc*64*H_+idx];
  float o=tanhf(v);
  o_prev[idx]=o; comb_t[idx]=o;
}

// ------ vocab GEMM with fused per-tile LSE partials + gold-logit gather ----------
__global__ __launch_bounds__(256)
void vocab_lse(const float* __restrict__ A, const float* __restrict__ Bv,
               const int* __restrict__ tgt,
               float* __restrict__ pmax, float* __restrict__ psum, float* __restrict__ gold)
{
  constexpr int BK=16;
  __shared__ float As[BK][132];
  __shared__ float Bs[BK][132];
  const int tid=threadIdx.x, tx=tid&15, ty=tid>>4;
  const int m0=blockIdx.x*128, n0=blockIdx.y*128;
  float acc[8][8];
#pragma unroll
  for(int i=0;i<8;i++)
#pragma unroll
    for(int j=0;j<8;j++) acc[i][j]=0.f;
  for(int k0=0;k0<H_;k0+=BK){
    for(int i=tid;i<512;i+=256){
      int r=i>>2,c=(i&3)*4;
      float4 v=make_float4(0.f,0.f,0.f,0.f);
      if(m0+r<NROW_) v=*(const float4*)(A+(size_t)(m0+r)*H_+k0+c);
      As[c+0][r]=v.x; As[c+1][r]=v.y; As[c+2][r]=v.z; As[c+3][r]=v.w;
    }
    for(int i=tid;i<512;i+=256){
      int r=i>>2,c=(i&3)*4;
      float4 v=*(const float4*)(Bv+(size_t)(n0+r)*H_+k0+c);
      Bs[c+0][r]=v.x; Bs[c+1][r]=v.y; Bs[c+2][r]=v.z; Bs[c+3][r]=v.w;
    }
    __syncthreads();
#pragma unroll
    for(int k=0;k<BK;k++){
      float a[8],bb[8];
#pragma unroll
      for(int i=0;i<8;i++) a[i]=As[k][ty*8+i];
#pragma unroll
      for(int j=0;j<8;j++) bb[j]=Bs[k][tx*8+j];
#pragma unroll
      for(int i=0;i<8;i++)
#pragma unroll
        for(int j=0;j<8;j++) acc[i][j]+=a[i]*bb[j];
    }
    __syncthreads();
  }
#pragma unroll
  for(int i=0;i<8;i++){
    int r=m0+ty*8+i;
    if(r>=NROW_) continue;
    float m=acc[i][0];
#pragma unroll
    for(int j=1;j<8;j++) m=fmaxf(m,acc[i][j]);
    for(int o=1;o<16;o<<=1) m=fmaxf(m,__shfl_xor(m,o,64));
    float s=0.f;
#pragma unroll
    for(int j=0;j<8;j++) s+=expf(acc[i][j]-m);
    for(int o=1;o<16;o<<=1) s+=__shfl_xor(s,o,64);
    if(tx==0){ pmax[(size_t)r*NTV_+blockIdx.y]=m; psum[(size_t)r*NTV_+blockIdx.y]=s; }
    int t=r>>6, b=r&63;
    int g=tgt[(t+1)*B_+b];
    int lj=g-n0;
    if(lj>=0 && lj<128 && (lj>>3)==tx) gold[r]=acc[i][lj&7];
  }
}

__global__ __launch_bounds__(256)
void lse_final(const float* __restrict__ pmax, const float* __restrict__ psum,
               const float* __restrict__ gold, float* __restrict__ gl)
{
  __shared__ float red[256];
  const int r=blockIdx.x, tid=threadIdx.x;
  float m=-INFINITY;
  for(int i=tid;i<NTV_;i+=256) m=fmaxf(m,pmax[(size_t)r*NTV_+i]);
  red[tid]=m; __syncthreads();
  for(int k=128;k>0;k>>=1){ if(tid<k) red[tid]=fmaxf(red[tid],red[tid+k]); __syncthreads(); }
  float M=red[0]; __syncthreads();
  float s=0.f;
  for(int i=tid;i<NTV_;i+=256) s+=psum[(size_t)r*NTV_+i]*expf(pmax[(size_t)r*NTV_+i]-M);
  red[tid]=s; __syncthreads();
  for(int k=128;k>0;k>>=1){ if(tid<k) red[tid]+=red[tid+k]; __syncthreads(); }
  if(tid==0) gl[r]=gold[r]-(M+logf(red[0]));
}

__global__ void final_sum(const float* __restrict__ gl, const int* __restrict__ tgt,
                          float* __restrict__ out)
{
  int b=threadIdx.x;
  float acc=0.f;
  for(int t=0;t<T1_;t++){
    int tk=tgt[(t+1)*B_+b];
    if(tk!=0) acc+=gl[t*B_+b];
  }
  out[b]=acc;
}

// =====================================================================================
extern "C" void kernel_launch(void* const* d_in, const int* in_sizes, int n_in,
                              void* d_out, int out_size, void* d_ws, size_t ws_size,
                              hipStream_t stream)
{
  (void)in_sizes; (void)n_in; (void)out_size; (void)ws_size;
  const int*   src    =(const int*)  d_in[0];
  const int*   tgt    =(const int*)  d_in[1];
  const int*   lens   =(const int*)  d_in[2];
  const float* src_emb=(const float*)d_in[3];
  const float* tgt_emb=(const float*)d_in[4];
  const float* Wih_f  =(const float*)d_in[5];
  const float* Whh_f  =(const float*)d_in[6];
  const float* b_f    =(const float*)d_in[7];
  const float* Wih_b  =(const float*)d_in[8];
  const float* Whh_b  =(const float*)d_in[9];
  const float* b_b    =(const float*)d_in[10];
  const float* dWih   =(const float*)d_in[11];
  const float* dWhh   =(const float*)d_in[12];
  const float* db     =(const float*)d_in[13];
  const float* W_h    =(const float*)d_in[14];
  const float* W_c    =(const float*)d_in[15];
  const float* W_att  =(const float*)d_in[16];
  const float* W_comb =(const float*)d_in[17];
  const float* W_voc  =(const float*)d_in[18];
  float* out=(float*)d_out;
  float* W  =(float*)d_ws;

  // ---- workspace layout (floats); total ~62.8M floats = 251 MB ----
  size_t off=0;
  auto AL=[&](size_t n){ size_t o=off; off+=n; return o; };
  const size_t oX    =AL((size_t)3072*E_);
  const size_t oXr   =AL((size_t)3072*E_);
  const size_t oY    =AL((size_t)NROW_*E_);
  const size_t oXpF  =AL((size_t)3072*H4_);
  const size_t oXpB  =AL((size_t)3072*H4_);
  const size_t oPartE=AL((size_t)2*8*64*H4_);
  const size_t oFwd  =AL((size_t)S_*64*H_);
  const size_t oBwdR =AL((size_t)S_*64*H_);
  const size_t oEncH =AL((size_t)64*S_*2048);
  const size_t oEncP =AL((size_t)64*S_*H_);
  const size_t oHf   =AL((size_t)2*64*H_);
  const size_t oCf   =AL((size_t)64*H_);
  const size_t oHb   =AL((size_t)2*64*H_);
  const size_t oCb   =AL((size_t)64*H_);
  const size_t oHcat =AL((size_t)64*2048);
  const size_t oCcat =AL((size_t)64*2048);
  const size_t oDh0  =AL((size_t)64*H_);
  const size_t oDc0  =AL((size_t)64*H_);
  const size_t oWhhC =AL((size_t)64*H4_);
  const size_t oOprev=AL((size_t)64*H_);
  const size_t oHt   =AL((size_t)64*H_);
  const size_t oPartD=AL((size_t)8*64*H4_);
  const size_t oCat  =AL((size_t)64*3072);
  const size_t oPartO=AL((size_t)4*64*H_);
  const size_t oComb =AL((size_t)NROW_*H_);
  const size_t oPmax =AL((size_t)NROW_*NTV_);
  const size_t oPsum =AL((size_t)NROW_*NTV_);
  const size_t oGold =AL((size_t)NROW_);
  const size_t oGl   =AL((size_t)NROW_);
  float* Wyp = W+oXpF;   // yproj aliases xproj_f (consumed before yproj is written)

  // ---- init recurrent state (h,c,o_prev = 0); oHf..oCb are contiguous ----
  hipMemsetAsync(W+oHf,   0, (size_t)(2*64*H_+64*H_+2*64*H_+64*H_)*sizeof(float), stream);
  hipMemsetAsync(W+oOprev,0, (size_t)64*H_*sizeof(float), stream);

  // ---- embeddings ----
  embed_all<<<dim3(3072+3072+NROW_),128,0,stream>>>(src,tgt,lens,src_emb,tgt_emb,
                                                    W+oX,W+oXr,W+oY);

  // ---- input projections for both encoder directions (bias folded in) ----
  gemm_nt<128,128,8,8><<<dim3(24,32),256,0,stream>>>(3072,E_, W+oX, E_, Wih_f,E_, W+oXpF,H4_, b_f);
  gemm_nt<128,128,8,8><<<dim3(24,32),256,0,stream>>>(3072,E_, W+oXr,E_, Wih_b,E_, W+oXpB,H4_, b_b);

  // ---- encoder: 48 steps, both directions per launch, split-K=8 ----
  for(int t=0;t<S_;t++){
    const float* hfc=W+oHf+(size_t)(t&1)*64*H_;  float* hfn=W+oHf+(size_t)((t+1)&1)*64*H_;
    const float* hbc=W+oHb+(size_t)(t&1)*64*H_;  float* hbn=W+oHb+(size_t)((t+1)&1)*64*H_;
    msmall_part<<<dim3(64,8,2),256,0,stream>>>(hfc,hbc,H_, Whh_f,Whh_b,H_, H4_,128, W+oPartE);
    enc_gates<<<dim3(256,2),256,0,stream>>>(W+oXpF+(size_t)t*64*H4_, W+oXpB+(size_t)t*64*H4_,
                                            W+oPartE, lens,
                                            hfc,hfn,W+oCf, hbc,hbn,W+oCb,
                                            W+oFwd+(size_t)t*64*H_, W+oBwdR+(size_t)t*64*H_, t);
  }

  // ---- enc_hiddens / final-state concat / projections ----
  gather_concat<<<dim3(3072+128),256,0,stream>>>(W+oFwd,W+oBwdR,lens,
                                                 W+oHf,W+oHb,W+oCf,W+oCb,
                                                 W+oEncH,W+oHcat,W+oCcat);
  gemm_nt<128,128,8,8><<<dim3(24,8),256,0,stream>>>(3072,2048, W+oEncH,2048, W_att,2048, W+oEncP,H_, nullptr);
  gemm_nt<64,64,4,4><<<dim3(1,16),256,0,stream>>>(64,2048, W+oHcat,2048, W_h,2048, W+oDh0,H_, nullptr);
  gemm_nt<64,64,4,4><<<dim3(1,16),256,0,stream>>>(64,2048, W+oCcat,2048, W_c,2048, W+oDc0,H_, nullptr);
  gemm_nt<64,64,4,4><<<dim3(1,64),256,0,stream>>>(64,H_, W+oDh0,H_, dWhh,H_, W+oWhhC,H4_, db);

  // ---- target-side input projection (cols 0..511 of dec_Wih), into alias ----
  gemm_nt<128,128,8,8><<<dim3(24,32),256,0,stream>>>(NROW_,E_, W+oY,E_, dWih,1536, Wyp,H4_, nullptr);

  // ---- decoder: 47 steps ----
  for(int t=0;t<T1_;t++){
    msmall_part<<<dim3(64,8,1),256,0,stream>>>(W+oOprev,W+oOprev,H_, dWih+512,dWih+512,1536,
                                               H4_,128, W+oPartD);
    dec_gates<<<dim3(256),256,0,stream>>>(Wyp+(size_t)t*64*H4_, W+oWhhC, W+oPartD, W+oDc0,
                                          W+oHt, W+oCat);
    attn_kernel<<<dim3(64),256,0,stream>>>(W+oHt, W+oEncP, W+oEncH, lens, W+oCat);
    msmall_part<<<dim3(16,4,1),256,0,stream>>>(W+oCat,W+oCat,3072, W_comb,W_comb,3072,
                                               H_,768, W+oPartO);
    ofin<<<dim3(256),256,0,stream>>>(W+oPartO, W+oOprev, W+oComb+(size_t)t*64*H_);
  }

  // ---- vocab projection + fused LSE + gold gather + masked time-sum ----
  vocab_lse<<<dim3(24,NTV_),256,0,stream>>>(W+oComb, W_voc, tgt, W+oPmax, W+oPsum, W+oGold);
  lse_final<<<dim3(NROW_),256,0,stream>>>(W+oPmax, W+oPsum, W+oGold, W+oGl);
  final_sum<<<dim3(1),64,0,stream>>>(W+oGl, tgt, out);
}

// Round 2
// 12405.865 us; speedup vs baseline: 1.4586x; 1.4586x over previous
//
#include <hip/hip_runtime.h>
#include <math.h>

// NMT seq2seq fwd: E=512, HE=HD=1024, V=32000, B=64, S=48, T=48.
// R2: big parallel GEMMs (vocab, xprojF/B, yproj, att-proj) -> bf16 MFMA
// (16x16x32, 128^2 tile, global_load_lds w16). Sequential LSTM loops stay fp32.
// Vocab GEMM fuses per-64col LSE partials + gold gather (no 385MB logits).

#define S_    48
#define B_    64
#define E_    512
#define H_    1024
#define H4_   4096
#define V_    32000
#define T1_   47
#define NROW_ 3008   // T1_*B_
#define NTV_  500    // V_/64 (per-wave 64-col tiles)

typedef __bf16 bf16x8 __attribute__((ext_vector_type(8)));
typedef float  f32x4  __attribute__((ext_vector_type(4)));
typedef unsigned short ushort_t;

__device__ __forceinline__ float sigm(float x){ return 1.f/(1.f+expf(-x)); }

__device__ __forceinline__ unsigned short f2bs(float f){   // RNE float->bf16
  unsigned u = __float_as_uint(f);
  u += 0x7fffu + ((u>>16)&1u);
  return (unsigned short)(u>>16);
}

__device__ __forceinline__ void gload16(const ushort_t* g, ushort_t* l){
  __builtin_amdgcn_global_load_lds((const __attribute__((address_space(1))) void*)g,
                                   (__attribute__((address_space(3))) void*)l, 16, 0, 0);
}

// ================= bf16 MFMA NT GEMM: C[M,N] = A[M,K] * B[N,K]^T (+bias) ============
// M = gridDim.x*128 (rows padded), N = gridDim.y*128. K multiple of 64.
__global__ __launch_bounds__(256)
void mfma_nt(const ushort_t* __restrict__ A, const ushort_t* __restrict__ B, int K,
             float* __restrict__ C, int ldc, const float* __restrict__ bias)
{
  __shared__ __align__(16) ushort_t As[128*64];
  __shared__ __align__(16) ushort_t Bs[128*64];
  const int tid=threadIdx.x, w=tid>>6, lane=tid&63;
  const int wm=w>>1, wn=w&1;
  const int m0=blockIdx.x*128, n0=blockIdx.y*128;
  const int rA=lane>>3, c8=(lane&7)*8;
  f32x4 acc[4][4];
#pragma unroll
  for(int i=0;i<4;i++)
#pragma unroll
    for(int j=0;j<4;j++) acc[i][j]=(f32x4){0.f,0.f,0.f,0.f};

  for(int k0=0;k0<K;k0+=64){
#pragma unroll
    for(int i=0;i<4;i++){
      int rb=w*32+i*8;
      gload16(A+(size_t)(m0+rb+rA)*K+k0+c8, &As[rb*64]);
      gload16(B+(size_t)(n0+rb+rA)*K+k0+c8, &Bs[rb*64]);
    }
    __syncthreads();
#pragma unroll
    for(int ks=0;ks<2;ks++){
      bf16x8 af[4], bfr[4];
#pragma unroll
      for(int i=0;i<4;i++){
        af[i] =*(const bf16x8*)&As[(wm*64+i*16+(lane&15))*64+ks*32+(lane>>4)*8];
        bfr[i]=*(const bf16x8*)&Bs[(wn*64+i*16+(lane&15))*64+ks*32+(lane>>4)*8];
      }
#pragma unroll
      for(int mi=0;mi<4;mi++)
#pragma unroll
        for(int ni=0;ni<4;ni++)
          acc[mi][ni]=__builtin_amdgcn_mfma_f32_16x16x32_bf16(af[mi],bfr[ni],acc[mi][ni],0,0,0);
    }
    __syncthreads();
  }
  const int cr=(lane>>4)*4, cc=lane&15;
#pragma unroll
  for(int mi=0;mi<4;mi++)
#pragma unroll
    for(int ni=0;ni<4;ni++){
      int col=n0+wn*64+ni*16+cc;
      float bv=bias? bias[col]:0.f;
#pragma unroll
      for(int j=0;j<4;j++){
        int row=m0+wm*64+mi*16+cr+j;
        C[(size_t)row*ldc+col]=acc[mi][ni][j]+bv;
      }
    }
}

// ===== vocab: bf16 MFMA GEMM + fused per-64col LSE partials + gold gather ===========
__global__ __launch_bounds__(256)
void mfma_vocab(const ushort_t* __restrict__ A, const ushort_t* __restrict__ B,
                const int* __restrict__ tgt,
                float* __restrict__ pmax, float* __restrict__ psum, float* __restrict__ gold)
{
  __shared__ __align__(16) ushort_t As[128*64];
  __shared__ __align__(16) ushort_t Bs[128*64];
  const int tid=threadIdx.x, w=tid>>6, lane=tid&63;
  const int wm=w>>1, wn=w&1;
  const int m0=blockIdx.x*128, n0=blockIdx.y*128;
  const int rA=lane>>3, c8=(lane&7)*8;
  f32x4 acc[4][4];
#pragma unroll
  for(int i=0;i<4;i++)
#pragma unroll
    for(int j=0;j<4;j++) acc[i][j]=(f32x4){0.f,0.f,0.f,0.f};

  for(int k0=0;k0<H_;k0+=64){
#pragma unroll
    for(int i=0;i<4;i++){
      int rb=w*32+i*8;
      gload16(A+(size_t)(m0+rb+rA)*H_+k0+c8, &As[rb*64]);
      gload16(B+(size_t)(n0+rb+rA)*H_+k0+c8, &Bs[rb*64]);
    }
    __syncthreads();
#pragma unroll
    for(int ks=0;ks<2;ks++){
      bf16x8 af[4], bfr[4];
#pragma unroll
      for(int i=0;i<4;i++){
        af[i] =*(const bf16x8*)&As[(wm*64+i*16+(lane&15))*64+ks*32+(lane>>4)*8];
        bfr[i]=*(const bf16x8*)&Bs[(wn*64+i*16+(lane&15))*64+ks*32+(lane>>4)*8];
      }
#pragma unroll
      for(int mi=0;mi<4;mi++)
#pragma unroll
        for(int ni=0;ni<4;ni++)
          acc[mi][ni]=__builtin_amdgcn_mfma_f32_16x16x32_bf16(af[mi],bfr[ni],acc[mi][ni],0,0,0);
    }
    __syncthreads();
  }
  // epilogue: per-row (64 cols of this wave) max & sumexp + gold gather
  const int tile=blockIdx.y*2+wn;
  const int cc=lane&15;
#pragma unroll
  for(int mi=0;mi<4;mi++){
#pragma unroll
    for(int j=0;j<4;j++){
      int row=m0+wm*64+mi*16+(lane>>4)*4+j;
      float m=acc[mi][0][j];
#pragma unroll
      for(int ni=1;ni<4;ni++) m=fmaxf(m,acc[mi][ni][j]);
      for(int o=1;o<16;o<<=1) m=fmaxf(m,__shfl_xor(m,o,64));
      float s=0.f;
#pragma unroll
      for(int ni=0;ni<4;ni++) s+=expf(acc[mi][ni][j]-m);
      for(int o=1;o<16;o<<=1) s+=__shfl_xor(s,o,64);
      if(row<NROW_){
        if(cc==0){ pmax[(size_t)row*NTV_+tile]=m; psum[(size_t)row*NTV_+tile]=s; }
        int g=tgt[((row>>6)+1)*B_+(row&63)];
        int lj=g-(n0+wn*64);
        if(lj>=0 && lj<64 && (lj&15)==cc) gold[row]=acc[mi][lj>>4][j];
      }
    }
  }
}

// ---------------- fp32 -> bf16 conversions ------------------------------------------
__global__ void f2b(const float* __restrict__ in, ushort_t* __restrict__ out, int n){
  int i=(blockIdx.x*256+threadIdx.x)*4;
  if(i>=n) return;
  float4 v=*(const float4*)(in+i);
  ushort4 o; o.x=f2bs(v.x); o.y=f2bs(v.y); o.z=f2bs(v.z); o.w=f2bs(v.w);
  *(ushort4*)(out+i)=o;
}
__global__ void f2b_str(const float* __restrict__ in, int ld, int cols,
                        ushort_t* __restrict__ out, int rows){
  int i=blockIdx.x*256+threadIdx.x;            // one per 4 elems
  int q=cols>>2, r=i/q, c=(i%q)*4;
  if(r>=rows) return;
  float4 v=*(const float4*)(in+(size_t)r*ld+c);
  ushort4 o; o.x=f2bs(v.x); o.y=f2bs(v.y); o.z=f2bs(v.z); o.w=f2bs(v.w);
  *(ushort4*)(out+(size_t)r*cols+c)=o;
}

// ---------------- fp32 NT GEMM (small, kept for dh0/dc0/whhC) -----------------------
template<int BM,int BN,int TM,int TN>
__global__ __launch_bounds__(256)
void gemm_nt(int M, int K,
             const float* __restrict__ A, int lda,
             const float* __restrict__ B, int ldb,
             float* __restrict__ C, int ldc,
             const float* __restrict__ bias)
{
  constexpr int BK=16;
  __shared__ float As[BK][BM+4];
  __shared__ float Bs[BK][BN+4];
  const int tid=threadIdx.x;
  constexpr int TX=BN/TN;
  const int tx=tid%TX, ty=tid/TX;
  const int m0=blockIdx.x*BM, n0=blockIdx.y*BN;
  float acc[TM][TN];
#pragma unroll
  for(int i=0;i<TM;i++)
#pragma unroll
    for(int j=0;j<TN;j++) acc[i][j]=0.f;
  for(int k0=0;k0<K;k0+=BK){
    for(int i=tid;i<BM*4;i+=256){
      int r=i>>2, c=(i&3)*4;
      float4 v=make_float4(0.f,0.f,0.f,0.f);
      if(m0+r<M) v=*(const float4*)(A+(size_t)(m0+r)*lda+k0+c);
      As[c+0][r]=v.x; As[c+1][r]=v.y; As[c+2][r]=v.z; As[c+3][r]=v.w;
    }
    for(int i=tid;i<BN*4;i+=256){
      int r=i>>2, c=(i&3)*4;
      float4 v=*(const float4*)(B+(size_t)(n0+r)*ldb+k0+c);
      Bs[c+0][r]=v.x; Bs[c+1][r]=v.y; Bs[c+2][r]=v.z; Bs[c+3][r]=v.w;
    }
    __syncthreads();
#pragma unroll
    for(int k=0;k<BK;k++){
      float a[TM], bb[TN];
#pragma unroll
      for(int i=0;i<TM;i++) a[i]=As[k][ty*TM+i];
#pragma unroll
      for(int j=0;j<TN;j++) bb[j]=Bs[k][tx*TN+j];
#pragma unroll
      for(int i=0;i<TM;i++)
#pragma unroll
        for(int j=0;j<TN;j++) acc[i][j]+=a[i]*bb[j];
    }
    __syncthreads();
  }
#pragma unroll
  for(int i=0;i<TM;i++){
    int r=m0+ty*TM+i;
    if(r>=M) continue;
#pragma unroll
    for(int j=0;j<TN;j++){
      int c=n0+tx*TN+j;
      float v=acc[i][j];
      if(bias) v+=bias[c];
      C[(size_t)r*ldc+c]=v;
    }
  }
}

// ------- small-M (=64) split-K partial GEMM; grid(ntiles, kchunks, dirs) ------------
__global__ __launch_bounds__(256)
void msmall_part(const float* __restrict__ A0, const float* __restrict__ A1, int lda,
                 const float* __restrict__ B0, const float* __restrict__ B1, int ldb,
                 int N, int kchunk, float* __restrict__ P)
{
  const int dir=blockIdx.z;
  const float* A=(dir?A1:A0)+(size_t)blockIdx.y*kchunk;
  const float* B=(dir?B1:B0)+(size_t)blockIdx.y*kchunk+(size_t)blockIdx.x*64*ldb;
  float* Po=P+((size_t)(dir*gridDim.y+blockIdx.y)*64*N)+blockIdx.x*64;
  __shared__ float As[16][68];
  __shared__ float Bs[16][68];
  const int tid=threadIdx.x, tx=tid&15, ty=tid>>4;
  float acc[4][4]={};
  for(int k0=0;k0<kchunk;k0+=16){
    {
      int r=tid>>2, c=(tid&3)*4;
      float4 v=*(const float4*)(A+(size_t)r*lda+k0+c);
      As[c+0][r]=v.x; As[c+1][r]=v.y; As[c+2][r]=v.z; As[c+3][r]=v.w;
      float4 w=*(const float4*)(B+(size_t)r*ldb+k0+c);
      Bs[c+0][r]=w.x; Bs[c+1][r]=w.y; Bs[c+2][r]=w.z; Bs[c+3][r]=w.w;
    }
    __syncthreads();
#pragma unroll
    for(int k=0;k<16;k++){
      float a[4],bb[4];
#pragma unroll
      for(int i=0;i<4;i++) a[i]=As[k][ty*4+i];
#pragma unroll
      for(int j=0;j<4;j++) bb[j]=Bs[k][tx*4+j];
#pragma unroll
      for(int i=0;i<4;i++)
#pragma unroll
        for(int j=0;j<4;j++) acc[i][j]+=a[i]*bb[j];
    }
    __syncthreads();
  }
#pragma unroll
  for(int i=0;i<4;i++)
#pragma unroll
    for(int j=0;j<4;j++)
      Po[(size_t)(ty*4+i)*N + tx*4+j]=acc[i][j];
}

// -------------------- embeddings (direct to bf16): X, Xrev, Y -----------------------
__global__ void embed_all(const int* __restrict__ src, const int* __restrict__ tgt,
                          const int* __restrict__ lens,
                          const float* __restrict__ se, const float* __restrict__ te,
                          ushort_t* __restrict__ X, ushort_t* __restrict__ Xr,
                          ushort_t* __restrict__ Y)
{
  int bi=blockIdx.x, tid=threadIdx.x;   // 128 thr, 4 elems each (E=512)
  const float* srcrow; ushort_t* dst;
  if(bi<3072){
    int s=bi>>6, b=bi&63;
    srcrow=se+(size_t)src[s*64+b]*E_; dst=X+(size_t)bi*E_;
  } else if(bi<6144){
    int r=bi-3072, t=r>>6, b=r&63;
    int L=lens[b]; int ts=(t<L)? L-1-t : t;
    srcrow=se+(size_t)src[ts*64+b]*E_; dst=Xr+(size_t)r*E_;
  } else {
    int r=bi-6144, t=r>>6, b=r&63;
    srcrow=te+(size_t)tgt[t*64+b]*E_; dst=Y+(size_t)r*E_;
  }
  float4 v=((const float4*)srcrow)[tid];
  ushort4 o; o.x=f2bs(v.x); o.y=f2bs(v.y); o.z=f2bs(v.z); o.w=f2bs(v.w);
  ((ushort4*)dst)[tid]=o;
}

// ------------- encoder step epilogue: sum partials, gates, mask, outputs ------------
__global__ __launch_bounds__(256)
void enc_gates(const float* __restrict__ xpf_t, const float* __restrict__ xpb_t,
               const float* __restrict__ part, const int* __restrict__ lens,
               const float* __restrict__ hf_cur, float* __restrict__ hf_nxt, float* __restrict__ cf,
               const float* __restrict__ hb_cur, float* __restrict__ hb_nxt, float* __restrict__ cb,
               float* __restrict__ fwd_t, float* __restrict__ bwdr_t, int t)
{
  const int dir=blockIdx.y;
  const int idx=blockIdx.x*256+threadIdx.x;     // b*1024+hj
  const int b=idx>>10, hj=idx&1023;
  const float* xp = dir? xpb_t : xpf_t;
  const float* P  = part + (size_t)dir*8*64*H4_;
  float g[4];
#pragma unroll
  for(int gi=0;gi<4;gi++){
    int col=hj+gi*1024;
    float v=xp[(size_t)b*H4_+col];
#pragma unroll
    for(int kc=0;kc<8;kc++) v+=P[(size_t)kc*64*H4_+(size_t)b*H4_+col];
    g[gi]=v;
  }
  const float* hc = dir? hb_cur: hf_cur;
  float* hn = dir? hb_nxt: hf_nxt;
  float* cc = dir? cb: cf;
  float c_old=cc[idx];
  float cn=sigm(g[1])*c_old+sigm(g[0])*tanhf(g[2]);
  float hv=sigm(g[3])*tanhf(cn);
  bool m = t<lens[b];
  cc[idx]= m? cn : c_old;
  hn[idx]= m? hv : hc[idx];
  float* ot = dir? bwdr_t : fwd_t;
  ot[idx]= m? hv : 0.f;
}

// --- build enc_hiddens (fp32 + bf16) with bwd un-reversal; concat final h/c ---------
__global__ void gather_concat(const float* __restrict__ fwd, const float* __restrict__ bwdR,
                              const int* __restrict__ lens,
                              const float* __restrict__ hfF, const float* __restrict__ hbF,
                              const float* __restrict__ cfF, const float* __restrict__ cbF,
                              float* __restrict__ encH, ushort_t* __restrict__ encHb,
                              float* __restrict__ hcat, float* __restrict__ ccat)
{
  int bi=blockIdx.x, tid=threadIdx.x;
  if(bi<3072){
    int b=bi/48, s=bi%48;
    float4* dst=(float4*)(encH+(size_t)bi*2048);
    const float4* f=(const float4*)(fwd+(size_t)(s*64+b)*H_);
    int L=lens[b]; int sr=(s<L)? L-1-s : s;
    const float4* w=(const float4*)(bwdR+(size_t)(sr*64+b)*H_);
    float4 vf=f[tid], vw=w[tid];
    dst[tid]=vf; dst[256+tid]=vw;
    ushort4 of, ow;
    of.x=f2bs(vf.x); of.y=f2bs(vf.y); of.z=f2bs(vf.z); of.w=f2bs(vf.w);
    ow.x=f2bs(vw.x); ow.y=f2bs(vw.y); ow.z=f2bs(vw.z); ow.w=f2bs(vw.w);
    ((ushort4*)(encHb+(size_t)bi*2048))[tid]=of;
    ((ushort4*)(encHb+(size_t)bi*2048+1024))[tid]=ow;
  } else if(bi<3136){
    int b=bi-3072;
    ((float4*)(hcat+(size_t)b*2048))[tid]      =((const float4*)(hfF+(size_t)b*H_))[tid];
    ((float4*)(hcat+(size_t)b*2048+1024))[tid] =((const float4*)(hbF+(size_t)b*H_))[tid];
  } else {
    int b=bi-3136;
    ((float4*)(ccat+(size_t)b*2048))[tid]      =((const float4*)(cfF+(size_t)b*H_))[tid];
    ((float4*)(ccat+(size_t)b*2048+1024))[tid] =((const float4*)(cbF+(size_t)b*H_))[tid];
  }
}

// ------------- decoder step epilogue (h,c NOT carried; c0 constant) -----------------
__global__ __launch_bounds__(256)
void dec_gates(const float* __restrict__ yp_t, const float* __restrict__ whhc,
               const float* __restrict__ part, const float* __restrict__ dc0,
               float* __restrict__ h_t, float* __restrict__ cat)
{
  const int idx=blockIdx.x*256+threadIdx.x;
  const int b=idx>>10, hj=idx&1023;
  float g[4];
#pragma unroll
  for(int gi=0;gi<4;gi++){
    int col=hj+gi*1024;
    float v=yp_t[(size_t)b*H4_+col]+whhc[(size_t)b*H4_+col];
#pragma unroll
    for(int kc=0;kc<8;kc++) v+=part[(size_t)kc*64*H4_+(size_t)b*H4_+col];
    g[gi]=v;
  }
  float cn=sigm(g[1])*dc0[idx]+sigm(g[0])*tanhf(g[2]);
  float hv=sigm(g[3])*tanhf(cn);
  h_t[idx]=hv;
  cat[(size_t)b*3072+2048+hj]=hv;
}

// ---- attention: e = enc_proj·h, masked softmax over S, a = alpha·enc_hiddens -------
__global__ __launch_bounds__(256)
void attn_kernel(const float* __restrict__ h_t, const float* __restrict__ encP,
                 const float* __restrict__ encH, const int* __restrict__ lens,
                 float* __restrict__ cat)
{
  __shared__ float hs[H_];
  __shared__ float es[S_];
  __shared__ float al[S_];
  const int b=blockIdx.x, tid=threadIdx.x;
  ((float4*)hs)[tid]=((const float4*)(h_t+(size_t)b*H_))[tid];
  __syncthreads();
  const int wave=tid>>6, lane=tid&63;
  for(int s=wave;s<S_;s+=4){
    const float* ep=encP+(size_t)(b*S_+s)*H_;
    float sum=0.f;
    for(int k=lane;k<H_;k+=64) sum+=ep[k]*hs[k];
    for(int o=32;o>0;o>>=1) sum+=__shfl_xor(sum,o,64);
    if(lane==0) es[s]=sum;
  }
  __syncthreads();
  if(tid<64){
    int L=lens[b];
    float e=(tid<S_ && tid<L)? es[tid] : -INFINITY;
    float m=e;
    for(int o=32;o>0;o>>=1) m=fmaxf(m,__shfl_xor(m,o,64));
    float p=(tid<S_)? expf(e-m):0.f;
    float sm=p;
    for(int o=32;o>0;o>>=1) sm+=__shfl_xor(sm,o,64);
    if(tid<S_) al[tid]=p/sm;
  }
  __syncthreads();
  for(int d=tid;d<2048;d+=256){
    float a=0.f;
    for(int s=0;s<S_;s++) a+=al[s]*encH[(size_t)(b*S_+s)*2048+d];
    cat[(size_t)b*3072+d]=a;
  }
}

// -------- finalize O = tanh(sum partials); feeds o_prev (fp32) + comb (bf16) --------
__global__ void ofin(const float* __restrict__ part, float* __restrict__ o_prev,
                     ushort_t* __restrict__ comb_t)
{
  int idx=blockIdx.x*256+threadIdx.x;   // 64*1024
  float v=0.f;
#pragma unroll
  for(int kc=0;kc<4;kc++) v+=part[(size_t)kc*64*H_+idx];
  float o=tanhf(v);
  o_prev[idx]=o; comb_t[idx]=f2bs(o);
}

__global__ __launch_bounds__(256)
void lse_final(const float* __restrict__ pmax, const float* __restrict__ psum,
               const float* __restrict__ gold, float* __restrict__ gl)
{
  __shared__ float red[256];
  const int r=blockIdx.x, tid=threadIdx.x;
  float m=-INFINITY;
  for(int i=tid;i<NTV_;i+=256) m=fmaxf(m,pmax[(size_t)r*NTV_+i]);
  red[tid]=m; __syncthreads();
  for(int k=128;k>0;k>>=1){ if(tid<k) red[tid]=fmaxf(red[tid],red[tid+k]); __syncthreads(); }
  float M=red[0]; __syncthreads();
  float s=0.f;
  for(int i=tid;i<NTV_;i+=256) s+=psum[(size_t)r*NTV_+i]*expf(pmax[(size_t)r*NTV_+i]-M);
  red[tid]=s; __syncthreads();
  for(int k=128;k>0;k>>=1){ if(tid<k) red[tid]+=red[tid+k]; __syncthreads(); }
  if(tid==0) gl[r]=gold[r]-(M+logf(red[0]));
}

__global__ void final_sum(const float* __restrict__ gl, const int* __restrict__ tgt,
                          float* __restrict__ out)
{
  int b=threadIdx.x;
  float acc=0.f;
  for(int t=0;t<T1_;t++){
    int tk=tgt[(t+1)*B_+b];
    if(tk!=0) acc+=gl[t*B_+b];
  }
  out[b]=acc;
}

// =====================================================================================
extern "C" void kernel_launch(void* const* d_in, const int* in_sizes, int n_in,
                              void* d_out, int out_size, void* d_ws, size_t ws_size,
                              hipStream_t stream)
{
  (void)in_sizes; (void)n_in; (void)out_size; (void)ws_size;
  const int*   src    =(const int*)  d_in[0];
  const int*   tgt    =(const int*)  d_in[1];
  const int*   lens   =(const int*)  d_in[2];
  const float* src_emb=(const float*)d_in[3];
  const float* tgt_emb=(const float*)d_in[4];
  const float* Wih_f  =(const float*)d_in[5];
  const float* Whh_f  =(const float*)d_in[6];
  const float* b_f    =(const float*)d_in[7];
  const float* Wih_b  =(const float*)d_in[8];
  const float* Whh_b  =(const float*)d_in[9];
  const float* b_b    =(const float*)d_in[10];
  const float* dWih   =(const float*)d_in[11];
  const float* dWhh   =(const float*)d_in[12];
  const float* db     =(const float*)d_in[13];
  const float* W_h    =(const float*)d_in[14];
  const float* W_c    =(const float*)d_in[15];
  const float* W_att  =(const float*)d_in[16];
  const float* W_comb =(const float*)d_in[17];
  const float* W_voc  =(const float*)d_in[18];
  float* out=(float*)d_out;
  float* W  =(float*)d_ws;

  // ---- fp32 workspace layout (floats); aliases documented inline ----
  size_t off=0;
  auto AL=[&](size_t n){ size_t o=off; off+=n; return o; };
  const size_t oXpF  =AL((size_t)3072*H4_);     // xprojF -> encHb(bf16) -> Wyp
  const size_t oXpB  =AL((size_t)3072*H4_);     // xprojB -> Wvb(bf16, +oPartE)
  const size_t oPartE=AL((size_t)2*8*64*H4_);   // enc partials (Wvb tail)
  const size_t oFwd  =AL((size_t)S_*64*H_);     // fwd outs -> CombB(bf16)
  const size_t oBwdR =AL((size_t)S_*64*H_);     // bwd-rev outs -> dec partials
  const size_t oEncH =AL((size_t)64*S_*2048);
  const size_t oEncP =AL((size_t)64*S_*H_);
  const size_t oHf   =AL((size_t)2*64*H_);
  const size_t oCf   =AL((size_t)64*H_);
  const size_t oHb   =AL((size_t)2*64*H_);
  const size_t oCb   =AL((size_t)64*H_);
  const size_t oHcat =AL((size_t)64*2048);
  const size_t oCcat =AL((size_t)64*2048);
  const size_t oDh0  =AL((size_t)64*H_);
  const size_t oDc0  =AL((size_t)64*H_);
  const size_t oWhhC =AL((size_t)64*H4_);
  const size_t oOprev=AL((size_t)64*H_);
  const size_t oHt   =AL((size_t)64*H_);
  const size_t oCat  =AL((size_t)64*3072);
  const size_t oPartO=AL((size_t)4*64*H_);
  const size_t oPmax =AL((size_t)NROW_*NTV_);
  const size_t oPsum =AL((size_t)NROW_*NTV_);
  const size_t oGold =AL((size_t)NROW_);
  const size_t oGl   =AL((size_t)NROW_);
  // ---- bf16 buffers (ushort units) ----
  const size_t oXb   =AL((size_t)3072*E_/2);
  const size_t oXrb  =AL((size_t)3072*E_/2);
  const size_t oYb   =AL((size_t)3072*E_/2);
  const size_t oWihfb=AL((size_t)H4_*E_/2);
  const size_t oWihbb=AL((size_t)H4_*E_/2);
  const size_t oWattb=AL((size_t)H_*2048/2);
  const size_t oWyb  =AL((size_t)H4_*E_/2);
  ushort_t* Xb    =(ushort_t*)(W+oXb);
  ushort_t* Xrb   =(ushort_t*)(W+oXrb);
  ushort_t* Yb    =(ushort_t*)(W+oYb);
  ushort_t* Wihfb =(ushort_t*)(W+oWihfb);
  ushort_t* Wihbb =(ushort_t*)(W+oWihbb);
  ushort_t* Wattb =(ushort_t*)(W+oWattb);
  ushort_t* dWihYb=(ushort_t*)(W+oWyb);
  // aliases (sequenced so lifetimes don't overlap):
  ushort_t* EncHb =(ushort_t*)(W+oXpF);    // after encoder, before yproj
  ushort_t* Wvb   =(ushort_t*)(W+oXpB);    // after encoder (spans oXpB+oPartE)
  ushort_t* CombB =(ushort_t*)(W+oFwd);    // decoder outputs, bf16 [3072][1024]
  float*    PartD =W+oBwdR;                // decoder split-K partials
  float*    Wyp   =W+oXpF;                 // y-projection [3072][4096]

  // ---- init recurrent state ----
  hipMemsetAsync(W+oHf,   0, (size_t)(6*64*H_)*sizeof(float), stream);  // oHf..oCb
  hipMemsetAsync(W+oOprev,0, (size_t)64*H_*sizeof(float), stream);

  // ---- embeddings (bf16) + weight conversions ----
  embed_all<<<dim3(3072+3072+NROW_),128,0,stream>>>(src,tgt,lens,src_emb,tgt_emb,Xb,Xrb,Yb);
  f2b<<<dim3(2048),256,0,stream>>>(Wih_f, Wihfb, H4_*E_);
  f2b<<<dim3(2048),256,0,stream>>>(Wih_b, Wihbb, H4_*E_);
  f2b<<<dim3(2048),256,0,stream>>>(W_att, Wattb, H_*2048);
  f2b_str<<<dim3(2048),256,0,stream>>>(dWih, 1536, E_, dWihYb, H4_);

  // ---- encoder input projections (bf16 MFMA, bias folded) ----
  mfma_nt<<<dim3(24,32),256,0,stream>>>(Xb,  Wihfb, E_, W+oXpF, H4_, b_f);
  mfma_nt<<<dim3(24,32),256,0,stream>>>(Xrb, Wihbb, E_, W+oXpB, H4_, b_b);

  // ---- encoder: 48 steps, both directions, split-K=8 (fp32) ----
  for(int t=0;t<S_;t++){
    const float* hfc=W+oHf+(size_t)(t&1)*64*H_;  float* hfn=W+oHf+(size_t)((t+1)&1)*64*H_;
    const float* hbc=W+oHb+(size_t)(t&1)*64*H_;  float* hbn=W+oHb+(size_t)((t+1)&1)*64*H_;
    msmall_part<<<dim3(64,8,2),256,0,stream>>>(hfc,hbc,H_, Whh_f,Whh_b,H_, H4_,128, W+oPartE);
    enc_gates<<<dim3(256,2),256,0,stream>>>(W+oXpF+(size_t)t*64*H4_, W+oXpB+(size_t)t*64*H4_,
                                            W+oPartE, lens,
                                            hfc,hfn,W+oCf, hbc,hbn,W+oCb,
                                            W+oFwd+(size_t)t*64*H_, W+oBwdR+(size_t)t*64*H_, t);
  }

  // ---- enc_hiddens (fp32 + bf16), final-state concat ----
  gather_concat<<<dim3(3072+128),256,0,stream>>>(W+oFwd,W+oBwdR,lens,
                                                 W+oHf,W+oHb,W+oCf,W+oCb,
                                                 W+oEncH,EncHb,W+oHcat,W+oCcat);
  // ---- attention projection (bf16 MFMA) ----
  mfma_nt<<<dim3(24,8),256,0,stream>>>(EncHb, Wattb, 2048, W+oEncP, H_, nullptr);
  // ---- vocab weight conversion (into dead xprojB region) ----
  f2b<<<dim3(32000),256,0,stream>>>(W_voc, Wvb, V_*H_);
  // ---- decoder init projections (fp32, tiny) ----
  gemm_nt<64,64,4,4><<<dim3(1,16),256,0,stream>>>(64,2048, W+oHcat,2048, W_h,2048, W+oDh0,H_, nullptr);
  gemm_nt<64,64,4,4><<<dim3(1,16),256,0,stream>>>(64,2048, W+oCcat,2048, W_c,2048, W+oDc0,H_, nullptr);
  gemm_nt<64,64,4,4><<<dim3(1,64),256,0,stream>>>(64,H_, W+oDh0,H_, dWhh,H_, W+oWhhC,H4_, db);
  // ---- target-side input projection (bf16 MFMA; overwrites EncHb region) ----
  mfma_nt<<<dim3(24,32),256,0,stream>>>(Yb, dWihYb, E_, Wyp, H4_, nullptr);

  // ---- decoder: 47 steps (fp32) ----
  for(int t=0;t<T1_;t++){
    msmall_part<<<dim3(64,8,1),256,0,stream>>>(W+oOprev,W+oOprev,H_, dWih+512,dWih+512,1536,
                                               H4_,128, PartD);
    dec_gates<<<dim3(256),256,0,stream>>>(Wyp+(size_t)t*64*H4_, W+oWhhC, PartD, W+oDc0,
                                          W+oHt, W+oCat);
    attn_kernel<<<dim3(64),256,0,stream>>>(W+oHt, W+oEncP, W+oEncH, lens, W+oCat);
    msmall_part<<<dim3(16,4,1),256,0,stream>>>(W+oCat,W+oCat,3072, W_comb,W_comb,3072,
                                               H_,768, W+oPartO);
    ofin<<<dim3(256),256,0,stream>>>(W+oPartO, W+oOprev, CombB+(size_t)t*64*H_);
  }

  // ---- vocab projection (bf16 MFMA) + fused LSE + gold + masked time-sum ----
  mfma_vocab<<<dim3(24,250),256,0,stream>>>(CombB, Wvb, tgt, W+oPmax, W+oPsum, W+oGold);
  lse_final<<<dim3(NROW_),256,0,stream>>>(W+oPmax, W+oPsum, W+oGold, W+oGl);
  final_sum<<<dim3(1),64,0,stream>>>(W+oGl, tgt, out);
}

// Round 3
// 11173.727 us; speedup vs baseline: 1.6195x; 1.1103x over previous
//
#include <hip/hip_runtime.h>
#include <math.h>

// NMT seq2seq fwd: E=512, HE=HD=1024, V=32000, B=64, S=48, T=48.
// R3: launch-count attack. Persistent encoder (1 launch, 48 steps, 1 grid-barrier
// per step) and persistent decoder (1 launch, 47 steps x 3 phases). Weight slices
// resident in LDS (128KB/block). All MFMA tiles use XOR-swizzled LDS (2-way max).
// ~18 launches total (was ~350).

#define S_    48
#define B_    64
#define E_    512
#define H_    1024
#define H4_   4096
#define V_    32000
#define T1_   47
#define NROW_ 3008
#define NTV_  500
#define NBE   128   // encoder blocks
#define NBD   64    // decoder blocks

typedef __bf16 bf16x8 __attribute__((ext_vector_type(8)));
typedef float  f32x4  __attribute__((ext_vector_type(4)));
typedef unsigned short ushort_t;

__device__ __forceinline__ float sigm(float x){ return 1.f/(1.f+expf(-x)); }
__device__ __forceinline__ unsigned short f2bs(float f){   // RNE float->bf16
  unsigned u=__float_as_uint(f); u+=0x7fffu+((u>>16)&1u); return (unsigned short)(u>>16);
}
__device__ __forceinline__ float b2f(ushort_t u){ return __uint_as_float(((unsigned)u)<<16); }
__device__ __forceinline__ void gload16(const ushort_t* g, ushort_t* l){
  __builtin_amdgcn_global_load_lds((const __attribute__((address_space(1))) void*)g,
                                   (__attribute__((address_space(3))) void*)l,16,0,0);
}

// --------- device-scope grid barrier (all blocks co-resident by construction) -------
__device__ __forceinline__ void gridbar(unsigned* bar, unsigned target){
  __syncthreads();
  if(threadIdx.x==0){
    __threadfence();   // release: publish my writes device-scope
    __hip_atomic_fetch_add(bar,1u,__ATOMIC_RELEASE,__HIP_MEMORY_SCOPE_AGENT);
    while(__hip_atomic_load(bar,__ATOMIC_RELAXED,__HIP_MEMORY_SCOPE_AGENT)<target)
      __builtin_amdgcn_s_sleep(2);
    __threadfence();   // acquire: invalidate stale caches
  }
  __syncthreads();
}

// ============ shared 128x128-tile MFMA machinery (XOR-swizzled LDS) =================
// stage one [128 rows x 64 cols] bf16 chunk; stored granule g holds logical g^(row&7)
__device__ __forceinline__ void stage128(const ushort_t* src, int ld, int k0,
                                         ushort_t* lds, int w, int lane){
  const int rA=lane>>3, gA=lane&7;
#pragma unroll
  for(int i=0;i<4;i++){
    int rb=w*32+i*8;
    int row=rb+rA;
    gload16(src+(size_t)row*ld+k0+(((gA)^(row&7))*8), &lds[rb*64]);
  }
}
__device__ __forceinline__ void mma128(const ushort_t* As, const ushort_t* Bs,
                                       f32x4 acc[4][4], int wm,int wn,int lane){
  const int l15=lane&15, l4=lane>>4;
#pragma unroll
  for(int ks=0;ks<2;ks++){
    bf16x8 af[4], bfr[4];
#pragma unroll
    for(int i=0;i<4;i++){
      int ra=wm*64+i*16+l15;
      af[i]=*(const bf16x8*)&As[ra*64+(((ks*4+l4)^(ra&7))*8)];
      int rb=wn*64+i*16+l15;
      bfr[i]=*(const bf16x8*)&Bs[rb*64+(((ks*4+l4)^(rb&7))*8)];
    }
#pragma unroll
    for(int mi=0;mi<4;mi++)
#pragma unroll
      for(int ni=0;ni<4;ni++)
        acc[mi][ni]=__builtin_amdgcn_mfma_f32_16x16x32_bf16(af[mi],bfr[ni],acc[mi][ni],0,0,0);
  }
}

// ---- proj3: z=0 xprojF, z=1 xprojB, z=2 yproj. M=3072, N=4096, K=512, fp32 out -----
__global__ __launch_bounds__(256)
void proj3(const ushort_t* __restrict__ Xb, const ushort_t* __restrict__ WfB, const float* __restrict__ bf,
           const ushort_t* __restrict__ XrB, const ushort_t* __restrict__ WbB, const float* __restrict__ bb,
           const ushort_t* __restrict__ Yb, const ushort_t* __restrict__ WyB,
           float* __restrict__ XpF, float* __restrict__ XpB, float* __restrict__ Yp)
{
  __shared__ __align__(16) ushort_t As[128*64];
  __shared__ __align__(16) ushort_t Bs[128*64];
  const ushort_t* A; const ushort_t* B; const float* bias; float* C;
  if(blockIdx.z==0){A=Xb;B=WfB;bias=bf;C=XpF;}
  else if(blockIdx.z==1){A=XrB;B=WbB;bias=bb;C=XpB;}
  else {A=Yb;B=WyB;bias=nullptr;C=Yp;}
  const int tid=threadIdx.x, w=tid>>6, lane=tid&63;
  const int wm=w>>1, wn=w&1;
  const int m0=blockIdx.x*128, n0=blockIdx.y*128;
  f32x4 acc[4][4];
#pragma unroll
  for(int i=0;i<4;i++)
#pragma unroll
    for(int j=0;j<4;j++) acc[i][j]=(f32x4){0.f,0.f,0.f,0.f};
  for(int k0=0;k0<E_;k0+=64){
    stage128(A+(size_t)m0*E_, E_, k0, As, w, lane);
    stage128(B+(size_t)n0*E_, E_, k0, Bs, w, lane);
    __syncthreads();
    mma128(As,Bs,acc,wm,wn,lane);
    __syncthreads();
  }
  const int cr=(lane>>4)*4, cc=lane&15;
#pragma unroll
  for(int mi=0;mi<4;mi++)
#pragma unroll
    for(int ni=0;ni<4;ni++){
      int col=n0+wn*64+ni*16+cc;
      float bv=bias? bias[col]:0.f;
#pragma unroll
      for(int j=0;j<4;j++){
        int row=m0+wm*64+mi*16+cr+j;
        C[(size_t)row*H4_+col]=acc[mi][ni][j]+bv;
      }
    }
}

// ---- attproj: encHb[3072][2048] @ W_att^T -> encPb bf16 [3072][1024] ----------------
__global__ __launch_bounds__(256)
void attproj(const ushort_t* __restrict__ A, const ushort_t* __restrict__ B,
             ushort_t* __restrict__ Cb)
{
  __shared__ __align__(16) ushort_t As[128*64];
  __shared__ __align__(16) ushort_t Bs[128*64];
  const int tid=threadIdx.x, w=tid>>6, lane=tid&63;
  const int wm=w>>1, wn=w&1;
  const int m0=blockIdx.x*128, n0=blockIdx.y*128;
  f32x4 acc[4][4];
#pragma unroll
  for(int i=0;i<4;i++)
#pragma unroll
    for(int j=0;j<4;j++) acc[i][j]=(f32x4){0.f,0.f,0.f,0.f};
  for(int k0=0;k0<2048;k0+=64){
    stage128(A+(size_t)m0*2048, 2048, k0, As, w, lane);
    stage128(B+(size_t)n0*2048, 2048, k0, Bs, w, lane);
    __syncthreads();
    mma128(As,Bs,acc,wm,wn,lane);
    __syncthreads();
  }
  const int cr=(lane>>4)*4, cc=lane&15;
#pragma unroll
  for(int mi=0;mi<4;mi++)
#pragma unroll
    for(int ni=0;ni<4;ni++){
      int col=n0+wn*64+ni*16+cc;
#pragma unroll
      for(int j=0;j<4;j++){
        int row=m0+wm*64+mi*16+cr+j;
        Cb[(size_t)row*H_+col]=f2bs(acc[mi][ni][j]);
      }
    }
}

// ---- vocab GEMM + fused per-64col LSE partials + gold gather ------------------------
__global__ __launch_bounds__(256)
void mfma_vocab(const ushort_t* __restrict__ A, const ushort_t* __restrict__ B,
                const int* __restrict__ tgt,
                float* __restrict__ pmax, float* __restrict__ psum, float* __restrict__ gold)
{
  __shared__ __align__(16) ushort_t As[128*64];
  __shared__ __align__(16) ushort_t Bs[128*64];
  const int tid=threadIdx.x, w=tid>>6, lane=tid&63;
  const int wm=w>>1, wn=w&1;
  const int m0=blockIdx.x*128, n0=blockIdx.y*128;
  f32x4 acc[4][4];
#pragma unroll
  for(int i=0;i<4;i++)
#pragma unroll
    for(int j=0;j<4;j++) acc[i][j]=(f32x4){0.f,0.f,0.f,0.f};
  for(int k0=0;k0<H_;k0+=64){
    stage128(A+(size_t)m0*H_, H_, k0, As, w, lane);
    stage128(B+(size_t)n0*H_, H_, k0, Bs, w, lane);
    __syncthreads();
    mma128(As,Bs,acc,wm,wn,lane);
    __syncthreads();
  }
  const int tile=blockIdx.y*2+wn;
  const int cc=lane&15;
#pragma unroll
  for(int mi=0;mi<4;mi++){
#pragma unroll
    for(int j=0;j<4;j++){
      int row=m0+wm*64+mi*16+(lane>>4)*4+j;
      float m=acc[mi][0][j];
#pragma unroll
      for(int ni=1;ni<4;ni++) m=fmaxf(m,acc[mi][ni][j]);
      for(int o=1;o<16;o<<=1) m=fmaxf(m,__shfl_xor(m,o,64));
      float s=0.f;
#pragma unroll
      for(int ni=0;ni<4;ni++) s+=expf(acc[mi][ni][j]-m);
      for(int o=1;o<16;o<<=1) s+=__shfl_xor(s,o,64);
      if(row<NROW_){
        if(cc==0){ pmax[(size_t)row*NTV_+tile]=m; psum[(size_t)row*NTV_+tile]=s; }
        int g=tgt[((row>>6)+1)*B_+(row&63)];
        int lj=g-(n0+wn*64);
        if(lj>=0 && lj<64 && (lj&15)==cc) gold[row]=acc[mi][lj>>4][j];
      }
    }
  }
}

// =================== persistent encoder: 48 steps, 1 barrier/step ===================
__global__ __launch_bounds__(256)
void enc_persist(const ushort_t* __restrict__ WhhB2,  // [2][4096][1024] bf16
                 const float* __restrict__ XpF, const float* __restrict__ XpB,
                 const int* __restrict__ lens,
                 ushort_t* __restrict__ hb,           // [2buf][2dir][64][1024]
                 float* __restrict__ cst,             // [2dir][64][1024]
                 ushort_t* __restrict__ outF, ushort_t* __restrict__ outBR,
                 unsigned* __restrict__ bar)
{
  __shared__ __align__(16) ushort_t Bp[64*1024];   // 128KB: resident Whh slice
  __shared__ __align__(16) ushort_t As[64*128];    // 16KB: streamed h chunk
  const int tid=threadIdx.x, w=tid>>6, lane=tid&63;
  const int blk=blockIdx.x, dir=blk>>6, j0=(blk&63)*16;
  const int l15=lane&15, l4=lane>>4;
  const ushort_t* Wd=WhhB2+(size_t)dir*H4_*H_;
  const float* xp = dir? XpB : XpF;
  float* cD = cst + (size_t)dir*65536;
  ushort_t* outD = dir? outBR : outF;

  // stage Whh rows {g*1024 + j0 + c : g in 0..3, c in 0..15} once
  for(int p=0;p<32;p++){
    int s=p*256+w*64+lane;
    int row=s>>7, g=s&127;
    int grow=((row>>4)<<10)+j0+(row&15);
    gload16(Wd+(size_t)grow*H_+((g^(row&7))*8), &Bp[(p*256+w*64)*8]);
  }
  __syncthreads();

  unsigned ep=0;
  for(int t=0;t<S_;t++){
    const ushort_t* hbR = hb + (size_t)(((t&1)*2+dir))*65536;
    ushort_t*       hbW = hb + (size_t)((((t+1)&1)*2+dir))*65536;
    f32x4 acc[4];
#pragma unroll
    for(int n=0;n<4;n++) acc[n]=(f32x4){0.f,0.f,0.f,0.f};
    for(int c=0;c<8;c++){
#pragma unroll
      for(int p=0;p<4;p++){
        int s=p*256+w*64+lane;
        int row=s>>4, g=s&15;
        gload16(hbR+(size_t)row*H_+c*128+((g^(row&7))*8), &As[(p*256+w*64)*8]);
      }
      __syncthreads();
#pragma unroll
      for(int ks=0;ks<4;ks++){
        int ra=w*16+l15;
        bf16x8 a=*(const bf16x8*)&As[ra*128+(((ks*4+l4)^(ra&7))*8)];
        int kk=c*4+ks;
#pragma unroll
        for(int n=0;n<4;n++){
          int rb=n*16+l15;
          bf16x8 b=*(const bf16x8*)&Bp[rb*H_+(((kk*4+l4)^(rb&7))*8)];
          acc[n]=__builtin_amdgcn_mfma_f32_16x16x32_bf16(a,b,acc[n],0,0,0);
        }
      }
      __syncthreads();
    }
    const int col=j0+l15;
#pragma unroll
    for(int j=0;j<4;j++){
      int row=w*16+l4*4+j;
      const float* xr=xp+(size_t)(t*64+row)*H4_;
      float g0=acc[0][j]+xr[col];
      float g1=acc[1][j]+xr[1024+col];
      float g2=acc[2][j]+xr[2048+col];
      float g3=acc[3][j]+xr[3072+col];
      size_t ix=(size_t)row*H_+col;
      float c_old=cD[ix];
      float cn=sigm(g1)*c_old+sigm(g0)*tanhf(g2);
      float hv=sigm(g3)*tanhf(cn);
      bool m=t<lens[row];
      cD[ix]= m? cn : c_old;
      hbW[ix]= m? f2bs(hv) : hbR[ix];
      outD[(size_t)(t*64+row)*H_+col]= m? f2bs(hv) : (ushort_t)0;
    }
    ep++;
    gridbar(bar, ep*(unsigned)NBE);
  }
}

// =================== persistent decoder: 47 steps x 3 phases ========================
__global__ __launch_bounds__(256)
void dec_persist(const ushort_t* __restrict__ WoB,    // [4096][1024] bf16 (dWih cols 512:1536)
                 const float* __restrict__ Yp,        // [47*64][4096]
                 const float* __restrict__ whhC,      // [64][4096]
                 const float* __restrict__ dc0,       // [64][1024]
                 const ushort_t* __restrict__ encPb,  // [64*48][1024]
                 const ushort_t* __restrict__ encHb,  // [64*48][2048]
                 const ushort_t* __restrict__ WcB,    // [1024][3072]
                 const int* __restrict__ lens,
                 ushort_t* __restrict__ opB,          // [64][1024]
                 ushort_t* __restrict__ hB,           // [64][1024]
                 ushort_t* __restrict__ catB,         // [64][3072]
                 ushort_t* __restrict__ combB,        // [3072][1024]
                 unsigned* __restrict__ bar)
{
  __shared__ __align__(16) ushort_t Bp[64*1024];   // 128KB: resident dWih_o slice
  __shared__ __align__(16) ushort_t dynA[64*128];  // 16KB
  __shared__ __align__(16) ushort_t dynB[16*128];  // 4KB
  __shared__ float es[S_], al[S_];
  const int tid=threadIdx.x, w=tid>>6, lane=tid&63;
  const int blk=blockIdx.x, j0=blk*16, b=blk;
  const int l15=lane&15, l4=lane>>4;

  for(int p=0;p<32;p++){
    int s=p*256+w*64+lane;
    int row=s>>7, g=s&127;
    int grow=((row>>4)<<10)+j0+(row&15);
    gload16(WoB+(size_t)grow*H_+((g^(row&7))*8), &Bp[(p*256+w*64)*8]);
  }
  __syncthreads();

  unsigned ep=0;
  for(int t=0;t<T1_;t++){
    // ---- P1: gates from opB @ Wo^T + Yp + whhC; c0 const ----
    f32x4 acc[4];
#pragma unroll
    for(int n=0;n<4;n++) acc[n]=(f32x4){0.f,0.f,0.f,0.f};
    for(int c=0;c<8;c++){
#pragma unroll
      for(int p=0;p<4;p++){
        int s=p*256+w*64+lane;
        int row=s>>4, g=s&15;
        gload16(opB+(size_t)row*H_+c*128+((g^(row&7))*8), &dynA[(p*256+w*64)*8]);
      }
      __syncthreads();
#pragma unroll
      for(int ks=0;ks<4;ks++){
        int ra=w*16+l15;
        bf16x8 a=*(const bf16x8*)&dynA[ra*128+(((ks*4+l4)^(ra&7))*8)];
        int kk=c*4+ks;
#pragma unroll
        for(int n=0;n<4;n++){
          int rb=n*16+l15;
          bf16x8 bb=*(const bf16x8*)&Bp[rb*H_+(((kk*4+l4)^(rb&7))*8)];
          acc[n]=__builtin_amdgcn_mfma_f32_16x16x32_bf16(a,bb,acc[n],0,0,0);
        }
      }
      __syncthreads();
    }
    {
      const int col=j0+l15;
#pragma unroll
      for(int j=0;j<4;j++){
        int row=w*16+l4*4+j;
        const float* yr=Yp+(size_t)(t*64+row)*H4_;
        const float* wr=whhC+(size_t)row*H4_;
        float g0=acc[0][j]+yr[col]     +wr[col];
        float g1=acc[1][j]+yr[1024+col]+wr[1024+col];
        float g2=acc[2][j]+yr[2048+col]+wr[2048+col];
        float g3=acc[3][j]+yr[3072+col]+wr[3072+col];
        float cn=sigm(g1)*dc0[(size_t)row*H_+col]+sigm(g0)*tanhf(g2);
        float hv=sigm(g3)*tanhf(cn);
        hB[(size_t)row*H_+col]=f2bs(hv);
        catB[(size_t)row*3072+2048+col]=f2bs(hv);
      }
    }
    ep++; gridbar(bar, ep*(unsigned)NBD);

    // ---- P2: attention for batch row b ----
    {
      float* hs=(float*)dynA;    // 4KB overlay
      for(int i=tid;i<H_;i+=256) hs[i]=b2f(hB[(size_t)b*H_+i]);
      __syncthreads();
      for(int s=w;s<S_;s+=4){
        const ushort_t* epr=encPb+((size_t)b*S_+s)*H_;
        float sum=0.f;
        for(int k=lane;k<H_;k+=64) sum+=b2f(epr[k])*hs[k];
        for(int o=32;o>0;o>>=1) sum+=__shfl_xor(sum,o,64);
        if(lane==0) es[s]=sum;
      }
      __syncthreads();
      if(tid<64){
        int L=lens[b];
        float e=(tid<S_&&tid<L)? es[tid] : -INFINITY;
        float m=e;
        for(int o=32;o>0;o>>=1) m=fmaxf(m,__shfl_xor(m,o,64));
        float p=(tid<S_)? expf(e-m):0.f;
        float sm=p;
        for(int o=32;o>0;o>>=1) sm+=__shfl_xor(sm,o,64);
        if(tid<S_) al[tid]=p/sm;
      }
      __syncthreads();
      for(int d=tid;d<2048;d+=256){
        float a=0.f;
        for(int s=0;s<S_;s++) a+=al[s]*b2f(encHb[((size_t)b*S_+s)*2048+d]);
        catB[(size_t)b*3072+d]=f2bs(a);
      }
    }
    ep++; gridbar(bar, ep*(unsigned)NBD);

    // ---- P3: O = tanh(catB @ Wcomb^T), cols j0..j0+15 ----
    f32x4 a3=(f32x4){0.f,0.f,0.f,0.f};
    for(int c=0;c<24;c++){
      int k0=c*128;
#pragma unroll
      for(int p=0;p<4;p++){
        int s=p*256+w*64+lane; int row=s>>4, g=s&15;
        gload16((const ushort_t*)catB+(size_t)row*3072+k0+((g^(row&7))*8), &dynA[(p*256+w*64)*8]);
      }
      { int s=w*64+lane; int row=s>>4, g=s&15;
        gload16(WcB+(size_t)(j0+row)*3072+k0+((g^(row&7))*8), &dynB[(w*64)*8]); }
      __syncthreads();
#pragma unroll
      for(int ks=0;ks<4;ks++){
        int ra=w*16+l15;
        bf16x8 a=*(const bf16x8*)&dynA[ra*128+(((ks*4+l4)^(ra&7))*8)];
        int rb=l15;
        bf16x8 bb=*(const bf16x8*)&dynB[rb*128+(((ks*4+l4)^(rb&7))*8)];
        a3=__builtin_amdgcn_mfma_f32_16x16x32_bf16(a,bb,a3,0,0,0);
      }
      __syncthreads();
    }
#pragma unroll
    for(int j=0;j<4;j++){
      int row=w*16+l4*4+j;
      float o=tanhf(a3[j]);
      opB[(size_t)row*H_+j0+l15]=f2bs(o);
      combB[((size_t)t*64+row)*H_+j0+l15]=f2bs(o);
    }
    ep++; gridbar(bar, ep*(unsigned)NBD);
  }
}

// ------------------ embeddings (direct to bf16): X, Xrev, Y -------------------------
__global__ void embed_all(const int* __restrict__ src, const int* __restrict__ tgt,
                          const int* __restrict__ lens,
                          const float* __restrict__ se, const float* __restrict__ te,
                          ushort_t* __restrict__ X, ushort_t* __restrict__ Xr,
                          ushort_t* __restrict__ Y)
{
  int bi=blockIdx.x, tid=threadIdx.x;
  const float* srcrow; ushort_t* dst;
  if(bi<3072){
    int s=bi>>6, b=bi&63;
    srcrow=se+(size_t)src[s*64+b]*E_; dst=X+(size_t)bi*E_;
  } else if(bi<6144){
    int r=bi-3072, t=r>>6, b=r&63;
    int L=lens[b]; int ts=(t<L)? L-1-t : t;
    srcrow=se+(size_t)src[ts*64+b]*E_; dst=Xr+(size_t)r*E_;
  } else {
    int r=bi-6144, t=r>>6, b=r&63;
    srcrow=te+(size_t)tgt[t*64+b]*E_; dst=Y+(size_t)r*E_;
  }
  float4 v=((const float4*)srcrow)[tid];
  ushort4 o; o.x=f2bs(v.x); o.y=f2bs(v.y); o.z=f2bs(v.z); o.w=f2bs(v.w);
  ((ushort4*)dst)[tid]=o;
}

// ------------- weight conversions fp32->bf16 (all but W_voc), grid-stride -----------
__global__ void prep_w(const float* __restrict__ Whhf,const float* __restrict__ Whhb,
                       const float* __restrict__ Wihf,const float* __restrict__ Wihb,
                       const float* __restrict__ Watt,const float* __restrict__ dWih,
                       const float* __restrict__ Wcomb,
                       ushort_t* __restrict__ WhhfB,ushort_t* __restrict__ WhhbB,
                       ushort_t* __restrict__ WihfB,ushort_t* __restrict__ WihbB,
                       ushort_t* __restrict__ WattB,ushort_t* __restrict__ dWihYb,
                       ushort_t* __restrict__ dWihOb,ushort_t* __restrict__ WcombB)
{
  const int NQ=6029312;
  for(int q=blockIdx.x*256+threadIdx.x; q<NQ; q+=gridDim.x*256){
    const float* src; ushort_t* dst; size_t si,di; int r;
    if(q<1048576){ si=(size_t)q*4; src=Whhf; dst=WhhfB; di=si; }
    else if(q<2097152){ r=q-1048576; si=(size_t)r*4; src=Whhb; dst=WhhbB; di=si; }
    else if(q<2621440){ r=q-2097152; si=(size_t)r*4; src=Wihf; dst=WihfB; di=si; }
    else if(q<3145728){ r=q-2621440; si=(size_t)r*4; src=Wihb; dst=WihbB; di=si; }
    else if(q<3670016){ r=q-3145728; si=(size_t)r*4; src=Watt; dst=WattB; di=si; }
    else if(q<4194304){ r=q-3670016; int row=r>>7, c4=(r&127)*4;
                        si=(size_t)row*1536+c4; src=dWih; dst=dWihYb; di=(size_t)row*512+c4; }
    else if(q<5242880){ r=q-4194304; int row=r>>8, c4=(r&255)*4;
                        si=(size_t)row*1536+512+c4; src=dWih; dst=dWihOb; di=(size_t)row*1024+c4; }
    else { r=q-5242880; si=(size_t)r*4; src=Wcomb; dst=WcombB; di=si; }
    float4 v=*(const float4*)(src+si);
    ushort4 o; o.x=f2bs(v.x);o.y=f2bs(v.y);o.z=f2bs(v.z);o.w=f2bs(v.w);
    *(ushort4*)(dst+di)=o;
  }
}

__global__ void f2b_voc(const float* __restrict__ in, ushort_t* __restrict__ out){
  for(size_t q=blockIdx.x*256+threadIdx.x; q<8192000; q+=(size_t)gridDim.x*256){
    float4 v=*(const float4*)(in+q*4);
    ushort4 o; o.x=f2bs(v.x);o.y=f2bs(v.y);o.z=f2bs(v.z);o.w=f2bs(v.w);
    *(ushort4*)(out+q*4)=o;
  }
}

// --- build enc_hiddens bf16 with bwd un-reversal; concat final h/c (fp32) -----------
__global__ void gather_concat(const ushort_t* __restrict__ outF, const ushort_t* __restrict__ outBR,
                              const int* __restrict__ lens,
                              const ushort_t* __restrict__ hb, const float* __restrict__ cst,
                              ushort_t* __restrict__ encHb,
                              float* __restrict__ hcat, float* __restrict__ ccat)
{
  int bi=blockIdx.x, tid=threadIdx.x;
  if(bi<3072){
    int b=bi/48, s=bi%48;
    int L=lens[b]; int sr=(s<L)? L-1-s : s;
    ((ushort4*)(encHb+(size_t)bi*2048))[tid]      =((const ushort4*)(outF +(size_t)(s*64+b)*H_))[tid];
    ((ushort4*)(encHb+(size_t)bi*2048+1024))[tid] =((const ushort4*)(outBR+(size_t)(sr*64+b)*H_))[tid];
  } else {
    int b=bi-3072;
    for(int i=tid;i<H_;i+=256){
      hcat[(size_t)b*2048+i]      = b2f(hb[(size_t)b*H_+i]);
      hcat[(size_t)b*2048+1024+i] = b2f(hb[65536+(size_t)b*H_+i]);
      ccat[(size_t)b*2048+i]      = cst[(size_t)b*H_+i];
      ccat[(size_t)b*2048+1024+i] = cst[65536+(size_t)b*H_+i];
    }
  }
}

// ---------------- fp32 NT GEMM (small: dh0/dc0/whhC) --------------------------------
template<int BM,int BN,int TM,int TN>
__global__ __launch_bounds__(256)
void gemm_nt(int M, int K,
             const float* __restrict__ A, int lda,
             const float* __restrict__ B, int ldb,
             float* __restrict__ C, int ldc,
             const float* __restrict__ bias)
{
  constexpr int BK=16;
  __shared__ float As[BK][BM+4];
  __shared__ float Bs[BK][BN+4];
  const int tid=threadIdx.x;
  constexpr int TX=BN/TN;
  const int tx=tid%TX, ty=tid/TX;
  const int m0=blockIdx.x*BM, n0=blockIdx.y*BN;
  float acc[TM][TN];
#pragma unroll
  for(int i=0;i<TM;i++)
#pragma unroll
    for(int j=0;j<TN;j++) acc[i][j]=0.f;
  for(int k0=0;k0<K;k0+=BK){
    for(int i=tid;i<BM*4;i+=256){
      int r=i>>2, c=(i&3)*4;
      float4 v=make_float4(0.f,0.f,0.f,0.f);
      if(m0+r<M) v=*(const float4*)(A+(size_t)(m0+r)*lda+k0+c);
      As[c+0][r]=v.x; As[c+1][r]=v.y; As[c+2][r]=v.z; As[c+3][r]=v.w;
    }
    for(int i=tid;i<BN*4;i+=256){
      int r=i>>2, c=(i&3)*4;
      float4 v=*(const float4*)(B+(size_t)(n0+r)*ldb+k0+c);
      Bs[c+0][r]=v.x; Bs[c+1][r]=v.y; Bs[c+2][r]=v.z; Bs[c+3][r]=v.w;
    }
    __syncthreads();
#pragma unroll
    for(int k=0;k<BK;k++){
      float a[TM], bb[TN];
#pragma unroll
      for(int i=0;i<TM;i++) a[i]=As[k][ty*TM+i];
#pragma unroll
      for(int j=0;j<TN;j++) bb[j]=Bs[k][tx*TN+j];
#pragma unroll
      for(int i=0;i<TM;i++)
#pragma unroll
        for(int j=0;j<TN;j++) acc[i][j]+=a[i]*bb[j];
    }
    __syncthreads();
  }
#pragma unroll
  for(int i=0;i<TM;i++){
    int r=m0+ty*TM+i;
    if(r>=M) continue;
#pragma unroll
    for(int j=0;j<TN;j++){
      int c=n0+tx*TN+j;
      float v=acc[i][j];
      if(bias) v+=bias[c];
      C[(size_t)r*ldc+c]=v;
    }
  }
}

__global__ __launch_bounds__(256)
void lse_final(const float* __restrict__ pmax, const float* __restrict__ psum,
               const float* __restrict__ gold, float* __restrict__ gl)
{
  __shared__ float red[256];
  const int r=blockIdx.x, tid=threadIdx.x;
  float m=-INFINITY;
  for(int i=tid;i<NTV_;i+=256) m=fmaxf(m,pmax[(size_t)r*NTV_+i]);
  red[tid]=m; __syncthreads();
  for(int k=128;k>0;k>>=1){ if(tid<k) red[tid]=fmaxf(red[tid],red[tid+k]); __syncthreads(); }
  float M=red[0]; __syncthreads();
  float s=0.f;
  for(int i=tid;i<NTV_;i+=256) s+=psum[(size_t)r*NTV_+i]*expf(pmax[(size_t)r*NTV_+i]-M);
  red[tid]=s; __syncthreads();
  for(int k=128;k>0;k>>=1){ if(tid<k) red[tid]+=red[tid+k]; __syncthreads(); }
  if(tid==0) gl[r]=gold[r]-(M+logf(red[0]));
}

__global__ void final_sum(const float* __restrict__ gl, const int* __restrict__ tgt,
                          float* __restrict__ out)
{
  int b=threadIdx.x;
  float acc=0.f;
  for(int t=0;t<T1_;t++){
    int tk=tgt[(t+1)*B_+b];
    if(tk!=0) acc+=gl[t*B_+b];
  }
  out[b]=acc;
}

// =====================================================================================
extern "C" void kernel_launch(void* const* d_in, const int* in_sizes, int n_in,
                              void* d_out, int out_size, void* d_ws, size_t ws_size,
                              hipStream_t stream)
{
  (void)in_sizes; (void)n_in; (void)out_size; (void)ws_size;
  const int*   src    =(const int*)  d_in[0];
  const int*   tgt    =(const int*)  d_in[1];
  const int*   lens   =(const int*)  d_in[2];
  const float* src_emb=(const float*)d_in[3];
  const float* tgt_emb=(const float*)d_in[4];
  const float* Wih_f  =(const float*)d_in[5];
  const float* Whh_f  =(const float*)d_in[6];
  const float* b_f    =(const float*)d_in[7];
  const float* Wih_b  =(const float*)d_in[8];
  const float* Whh_b  =(const float*)d_in[9];
  const float* b_b    =(const float*)d_in[10];
  const float* dWih   =(const float*)d_in[11];
  const float* dWhh   =(const float*)d_in[12];
  const float* db     =(const float*)d_in[13];
  const float* W_h    =(const float*)d_in[14];
  const float* W_c    =(const float*)d_in[15];
  const float* W_att  =(const float*)d_in[16];
  const float* W_comb =(const float*)d_in[17];
  const float* W_voc  =(const float*)d_in[18];
  float* out=(float*)d_out;
  float* W  =(float*)d_ws;

  size_t off=0;
  auto AL=[&](size_t n){ size_t o=off; off+=n; return o; };
  // ---- fp32 region ----
  const size_t oXpF  =AL((size_t)3072*H4_);   // dead after encoder -> WvocB + LSE bufs
  const size_t oXpB  =AL((size_t)3072*H4_);
  const size_t oYp   =AL((size_t)3072*H4_);
  const size_t oCst  =AL((size_t)2*64*H_);
  const size_t oHcat =AL((size_t)64*2048);
  const size_t oCcat =AL((size_t)64*2048);
  const size_t oDh0  =AL((size_t)64*H_);
  const size_t oDc0  =AL((size_t)64*H_);
  const size_t oWhhC =AL((size_t)64*H4_);
  const size_t oBar  =AL((size_t)64);
  // ---- bf16 region (ushort counts / 2) ----
  const size_t oXb    =AL((size_t)3072*E_/2);
  const size_t oXrb   =AL((size_t)3072*E_/2);
  const size_t oYb    =AL((size_t)3072*E_/2);
  const size_t oWhhfB =AL((size_t)H4_*H_/2);
  const size_t oWhhbB =AL((size_t)H4_*H_/2);
  const size_t oWihfB =AL((size_t)H4_*E_/2);
  const size_t oWihbB =AL((size_t)H4_*E_/2);
  const size_t oWattB =AL((size_t)H_*2048/2);
  const size_t odWihYb=AL((size_t)H4_*E_/2);
  const size_t odWihOb=AL((size_t)H4_*H_/2);
  const size_t oWcombB=AL((size_t)H_*3072/2);
  const size_t oHbuf  =AL((size_t)2*2*64*H_/2);   // [2buf][2dir][64][1024]
  const size_t oOutF  =AL((size_t)S_*64*H_/2);    // alias: combB in decoder
  const size_t oOutBR =AL((size_t)S_*64*H_/2);
  const size_t oEncHb =AL((size_t)3072*2048/2);
  const size_t oEncPb =AL((size_t)3072*H_/2);
  const size_t oHB    =AL((size_t)64*H_/2);
  const size_t oCatB  =AL((size_t)64*3072/2);
  const size_t oOpB   =AL((size_t)64*H_/2);

  ushort_t* Xb    =(ushort_t*)(W+oXb);
  ushort_t* Xrb   =(ushort_t*)(W+oXrb);
  ushort_t* Yb    =(ushort_t*)(W+oYb);
  ushort_t* WhhfB =(ushort_t*)(W+oWhhfB);
  ushort_t* WihfB =(ushort_t*)(W+oWihfB);
  ushort_t* WihbB =(ushort_t*)(W+oWihbB);
  ushort_t* WattB =(ushort_t*)(W+oWattB);
  ushort_t* dWihYb=(ushort_t*)(W+odWihYb);
  ushort_t* dWihOb=(ushort_t*)(W+odWihOb);
  ushort_t* WcombB=(ushort_t*)(W+oWcombB);
  ushort_t* Hbuf  =(ushort_t*)(W+oHbuf);
  ushort_t* OutF  =(ushort_t*)(W+oOutF);
  ushort_t* OutBR =(ushort_t*)(W+oOutBR);
  ushort_t* EncHb =(ushort_t*)(W+oEncHb);
  ushort_t* EncPb =(ushort_t*)(W+oEncPb);
  ushort_t* HB    =(ushort_t*)(W+oHB);
  ushort_t* CatB  =(ushort_t*)(W+oCatB);
  ushort_t* OpB   =(ushort_t*)(W+oOpB);
  // aliases in dead XpF/XpB region (both dead after encoder):
  ushort_t* WvocB =(ushort_t*)(W+oXpF);           // 16.38M floats
  float* pmax = W+oXpF+16500000;
  float* psum = pmax+ (size_t)NROW_*NTV_;
  float* gold = psum+ (size_t)NROW_*NTV_;
  float* gl   = gold+ NROW_;
  ushort_t* CombB =(ushort_t*)(W+oOutF);          // decoder O outputs (outF dead)
  unsigned* bar0=(unsigned*)(W+oBar);
  unsigned* bar1=bar0+16;

  // ---- per-call init (re-zeroed on every replay) ----
  hipMemsetAsync(W+oBar, 0, 64*sizeof(float), stream);
  hipMemsetAsync(W+oCst, 0, (size_t)2*64*H_*sizeof(float), stream);
  hipMemsetAsync(Hbuf,   0, (size_t)2*2*64*H_*sizeof(ushort_t), stream);
  hipMemsetAsync(OpB,    0, (size_t)64*H_*sizeof(ushort_t), stream);

  // ---- prep ----
  embed_all<<<dim3(3072+3072+NROW_),128,0,stream>>>(src,tgt,lens,src_emb,tgt_emb,Xb,Xrb,Yb);
  prep_w<<<dim3(2048),256,0,stream>>>(Whh_f,Whh_b,Wih_f,Wih_b,W_att,dWih,W_comb,
                                      WhhfB,(ushort_t*)(W+oWhhbB),WihfB,WihbB,WattB,
                                      dWihYb,dWihOb,WcombB);
  proj3<<<dim3(24,32,3),256,0,stream>>>(Xb,WihfB,b_f, Xrb,WihbB,b_b, Yb,dWihYb,
                                        W+oXpF,W+oXpB,W+oYp);

  // ---- encoder (1 launch, 48 steps) ----
  enc_persist<<<dim3(NBE),256,0,stream>>>(WhhfB, W+oXpF, W+oXpB, lens,
                                          Hbuf, W+oCst, OutF, OutBR, bar0);

  // ---- mid section ----
  gather_concat<<<dim3(3136),256,0,stream>>>(OutF,OutBR,lens,Hbuf,W+oCst,
                                             EncHb,W+oHcat,W+oCcat);
  f2b_voc<<<dim3(2048),256,0,stream>>>(W_voc, WvocB);
  attproj<<<dim3(24,8),256,0,stream>>>(EncHb, WattB, EncPb);
  gemm_nt<64,64,4,4><<<dim3(1,16),256,0,stream>>>(64,2048, W+oHcat,2048, W_h,2048, W+oDh0,H_, nullptr);
  gemm_nt<64,64,4,4><<<dim3(1,16),256,0,stream>>>(64,2048, W+oCcat,2048, W_c,2048, W+oDc0,H_, nullptr);
  gemm_nt<64,64,4,4><<<dim3(1,64),256,0,stream>>>(64,H_, W+oDh0,H_, dWhh,H_, W+oWhhC,H4_, db);

  // ---- decoder (1 launch, 47 steps) ----
  dec_persist<<<dim3(NBD),256,0,stream>>>(dWihOb, W+oYp, W+oWhhC, W+oDc0,
                                          EncPb, EncHb, WcombB, lens,
                                          OpB, HB, CatB, CombB, bar1);

  // ---- vocab + LSE + output ----
  mfma_vocab<<<dim3(24,NTV_/2),256,0,stream>>>(CombB, WvocB, tgt, pmax, psum, gold);
  lse_final<<<dim3(NROW_),256,0,stream>>>(pmax, psum, gold, gl);
  final_sum<<<dim3(1),64,0,stream>>>(gl, tgt, out);
}

// Round 4
// 5094.170 us; speedup vs baseline: 3.5522x; 2.1934x over previous
//
#include <hip/hip_runtime.h>
#include <math.h>

// NMT seq2seq fwd: E=512, HE=HD=1024, V=32000, B=64, S=48, T=48.
// R4: decoder restructure. G = encH @ Wcomb[:, :2048]^T precomputed once ->
// attention context becomes alpha @ G (per-b, L2-resident). Decoder loop:
// PA gates-MFMA (Wo LDS-resident, dbuf chunk-64 staging), PB per-b e/softmax/alphaG
// (vectorized), PC O = tanh(alphaG + h@WcH^T) MFMA. Encoder gets same dbuf staging.

#define S_    48
#define B_    64
#define E_    512
#define H_    1024
#define H4_   4096
#define V_    32000
#define T1_   47
#define NROW_ 3008
#define NTV_  500
#define NBE   128   // encoder blocks
#define NBD   64    // decoder blocks

typedef __bf16 bf16x8 __attribute__((ext_vector_type(8)));
typedef float  f32x4  __attribute__((ext_vector_type(4)));
typedef unsigned short ushort_t;

__device__ __forceinline__ float sigm(float x){ return 1.f/(1.f+expf(-x)); }
__device__ __forceinline__ unsigned short f2bs(float f){   // RNE float->bf16
  unsigned u=__float_as_uint(f); u+=0x7fffu+((u>>16)&1u); return (unsigned short)(u>>16);
}
__device__ __forceinline__ float b2f(ushort_t u){ return __uint_as_float(((unsigned)u)<<16); }
__device__ __forceinline__ void gload16(const ushort_t* g, ushort_t* l){
  __builtin_amdgcn_global_load_lds((const __attribute__((address_space(1))) void*)g,
                                   (__attribute__((address_space(3))) void*)l,16,0,0);
}

// --------- device-scope grid barrier (all blocks co-resident by construction) -------
__device__ __forceinline__ void gridbar(unsigned* bar, unsigned target){
  __syncthreads();
  if(threadIdx.x==0){
    __threadfence();
    __hip_atomic_fetch_add(bar,1u,__ATOMIC_RELEASE,__HIP_MEMORY_SCOPE_AGENT);
    while(__hip_atomic_load(bar,__ATOMIC_RELAXED,__HIP_MEMORY_SCOPE_AGENT)<target)
      __builtin_amdgcn_s_sleep(2);
    __threadfence();
  }
  __syncthreads();
}

// ============ shared 128x128-tile MFMA machinery (XOR-swizzled LDS) =================
__device__ __forceinline__ void stage128(const ushort_t* src, int ld, int k0,
                                         ushort_t* lds, int w, int lane){
  const int rA=lane>>3, gA=lane&7;
#pragma unroll
  for(int i=0;i<4;i++){
    int rb=w*32+i*8;
    int row=rb+rA;
    gload16(src+(size_t)row*ld+k0+(((gA)^(row&7))*8), &lds[rb*64]);
  }
}
__device__ __forceinline__ void mma128(const ushort_t* As, const ushort_t* Bs,
                                       f32x4 acc[4][4], int wm,int wn,int lane){
  const int l15=lane&15, l4=lane>>4;
#pragma unroll
  for(int ks=0;ks<2;ks++){
    bf16x8 af[4], bfr[4];
#pragma unroll
    for(int i=0;i<4;i++){
      int ra=wm*64+i*16+l15;
      af[i]=*(const bf16x8*)&As[ra*64+(((ks*4+l4)^(ra&7))*8)];
      int rb=wn*64+i*16+l15;
      bfr[i]=*(const bf16x8*)&Bs[rb*64+(((ks*4+l4)^(rb&7))*8)];
    }
#pragma unroll
    for(int mi=0;mi<4;mi++)
#pragma unroll
      for(int ni=0;ni<4;ni++)
        acc[mi][ni]=__builtin_amdgcn_mfma_f32_16x16x32_bf16(af[mi],bfr[ni],acc[mi][ni],0,0,0);
  }
}

// ---- proj3: z=0 xprojF, z=1 xprojB, z=2 yproj. M=3072, N=4096, K=512, fp32 out -----
__global__ __launch_bounds__(256)
void proj3(const ushort_t* __restrict__ Xb, const ushort_t* __restrict__ WfB, const float* __restrict__ bf,
           const ushort_t* __restrict__ XrB, const ushort_t* __restrict__ WbB, const float* __restrict__ bb,
           const ushort_t* __restrict__ Yb, const ushort_t* __restrict__ WyB,
           float* __restrict__ XpF, float* __restrict__ XpB, float* __restrict__ Yp)
{
  __shared__ __align__(16) ushort_t As[128*64];
  __shared__ __align__(16) ushort_t Bs[128*64];
  const ushort_t* A; const ushort_t* B; const float* bias; float* C;
  if(blockIdx.z==0){A=Xb;B=WfB;bias=bf;C=XpF;}
  else if(blockIdx.z==1){A=XrB;B=WbB;bias=bb;C=XpB;}
  else {A=Yb;B=WyB;bias=nullptr;C=Yp;}
  const int tid=threadIdx.x, w=tid>>6, lane=tid&63;
  const int wm=w>>1, wn=w&1;
  const int m0=blockIdx.x*128, n0=blockIdx.y*128;
  f32x4 acc[4][4];
#pragma unroll
  for(int i=0;i<4;i++)
#pragma unroll
    for(int j=0;j<4;j++) acc[i][j]=(f32x4){0.f,0.f,0.f,0.f};
  for(int k0=0;k0<E_;k0+=64){
    stage128(A+(size_t)m0*E_, E_, k0, As, w, lane);
    stage128(B+(size_t)n0*E_, E_, k0, Bs, w, lane);
    __syncthreads();
    mma128(As,Bs,acc,wm,wn,lane);
    __syncthreads();
  }
  const int cr=(lane>>4)*4, cc=lane&15;
#pragma unroll
  for(int mi=0;mi<4;mi++)
#pragma unroll
    for(int ni=0;ni<4;ni++){
      int col=n0+wn*64+ni*16+cc;
      float bv=bias? bias[col]:0.f;
#pragma unroll
      for(int j=0;j<4;j++){
        int row=m0+wm*64+mi*16+cr+j;
        C[(size_t)row*H4_+col]=acc[mi][ni][j]+bv;
      }
    }
}

// ---- generic bf16-out NT GEMM, M=3072, N=1024: used for encP and G -----------------
__global__ __launch_bounds__(256)
void bproj(const ushort_t* __restrict__ A, int lda,
           const ushort_t* __restrict__ B, int ldb, int K,
           ushort_t* __restrict__ Cb)
{
  __shared__ __align__(16) ushort_t As[128*64];
  __shared__ __align__(16) ushort_t Bs[128*64];
  const int tid=threadIdx.x, w=tid>>6, lane=tid&63;
  const int wm=w>>1, wn=w&1;
  const int m0=blockIdx.x*128, n0=blockIdx.y*128;
  f32x4 acc[4][4];
#pragma unroll
  for(int i=0;i<4;i++)
#pragma unroll
    for(int j=0;j<4;j++) acc[i][j]=(f32x4){0.f,0.f,0.f,0.f};
  for(int k0=0;k0<K;k0+=64){
    stage128(A+(size_t)m0*lda, lda, k0, As, w, lane);
    stage128(B+(size_t)n0*ldb, ldb, k0, Bs, w, lane);
    __syncthreads();
    mma128(As,Bs,acc,wm,wn,lane);
    __syncthreads();
  }
  const int cr=(lane>>4)*4, cc=lane&15;
#pragma unroll
  for(int mi=0;mi<4;mi++)
#pragma unroll
    for(int ni=0;ni<4;ni++){
      int col=n0+wn*64+ni*16+cc;
#pragma unroll
      for(int j=0;j<4;j++){
        int row=m0+wm*64+mi*16+cr+j;
        Cb[(size_t)row*H_+col]=f2bs(acc[mi][ni][j]);
      }
    }
}

// ---- vocab GEMM + fused per-64col LSE partials + gold gather ------------------------
__global__ __launch_bounds__(256)
void mfma_vocab(const ushort_t* __restrict__ A, const ushort_t* __restrict__ B,
                const int* __restrict__ tgt,
                float* __restrict__ pmax, float* __restrict__ psum, float* __restrict__ gold)
{
  __shared__ __align__(16) ushort_t As[128*64];
  __shared__ __align__(16) ushort_t Bs[128*64];
  const int tid=threadIdx.x, w=tid>>6, lane=tid&63;
  const int wm=w>>1, wn=w&1;
  const int m0=blockIdx.x*128, n0=blockIdx.y*128;
  f32x4 acc[4][4];
#pragma unroll
  for(int i=0;i<4;i++)
#pragma unroll
    for(int j=0;j<4;j++) acc[i][j]=(f32x4){0.f,0.f,0.f,0.f};
  for(int k0=0;k0<H_;k0+=64){
    stage128(A+(size_t)m0*H_, H_, k0, As, w, lane);
    stage128(B+(size_t)n0*H_, H_, k0, Bs, w, lane);
    __syncthreads();
    mma128(As,Bs,acc,wm,wn,lane);
    __syncthreads();
  }
  const int tile=blockIdx.y*2+wn;
  const int cc=lane&15;
#pragma unroll
  for(int mi=0;mi<4;mi++){
#pragma unroll
    for(int j=0;j<4;j++){
      int row=m0+wm*64+mi*16+(lane>>4)*4+j;
      float m=acc[mi][0][j];
#pragma unroll
      for(int ni=1;ni<4;ni++) m=fmaxf(m,acc[mi][ni][j]);
      for(int o=1;o<16;o<<=1) m=fmaxf(m,__shfl_xor(m,o,64));
      float s=0.f;
#pragma unroll
      for(int ni=0;ni<4;ni++) s+=expf(acc[mi][ni][j]-m);
      for(int o=1;o<16;o<<=1) s+=__shfl_xor(s,o,64);
      if(row<NROW_){
        if(cc==0){ pmax[(size_t)row*NTV_+tile]=m; psum[(size_t)row*NTV_+tile]=s; }
        int g=tgt[((row>>6)+1)*B_+(row&63)];
        int lj=g-(n0+wn*64);
        if(lj>=0 && lj<64 && (lj&15)==cc) gold[row]=acc[mi][lj>>4][j];
      }
    }
  }
}

// =================== persistent encoder: 48 steps, 1 barrier/step ===================
__global__ __launch_bounds__(256)
void enc_persist(const ushort_t* __restrict__ WhhB2,
                 const float* __restrict__ XpF, const float* __restrict__ XpB,
                 const int* __restrict__ lens,
                 ushort_t* __restrict__ hb, float* __restrict__ cst,
                 ushort_t* __restrict__ outF, ushort_t* __restrict__ outBR,
                 unsigned* __restrict__ bar)
{
  __shared__ __align__(16) ushort_t Bp[64*1024];   // 128KB resident Whh slice
  __shared__ __align__(16) ushort_t As[2][64*64];  // 2x8KB dbuf
  const int tid=threadIdx.x, w=tid>>6, lane=tid&63;
  const int blk=blockIdx.x, dir=blk>>6, j0=(blk&63)*16;
  const int l15=lane&15, l4=lane>>4;
  const ushort_t* Wd=WhhB2+(size_t)dir*H4_*H_;
  const float* xp = dir? XpB : XpF;
  float* cD = cst + (size_t)dir*65536;
  ushort_t* outD = dir? outBR : outF;

  for(int p=0;p<32;p++){
    int s=p*256+w*64+lane;
    int row=s>>7, g=s&127;
    int grow=((row>>4)<<10)+j0+(row&15);
    gload16(Wd+(size_t)grow*H_+((g^(row&7))*8), &Bp[(p*256+w*64)*8]);
  }
  __syncthreads();

  unsigned ep=0;
  for(int t=0;t<S_;t++){
    const ushort_t* hbR = hb + (size_t)(((t&1)*2+dir))*65536;
    ushort_t*       hbW = hb + (size_t)((((t+1)&1)*2+dir))*65536;
    f32x4 acc[4];
#pragma unroll
    for(int n=0;n<4;n++) acc[n]=(f32x4){0.f,0.f,0.f,0.f};
    // chunk-64 double-buffered staging of h
#pragma unroll 1
    for(int p=0;p<2;p++){
      int s=p*256+w*64+lane, row=s>>3, g=s&7;
      gload16(hbR+(size_t)row*H_+((g^(row&7))*8), &As[0][(p*256+w*64)*8]);
    }
    __syncthreads();
    for(int c=0;c<16;c++){
      if(c<15){
        int k0=(c+1)*64;
#pragma unroll 1
        for(int p=0;p<2;p++){
          int s=p*256+w*64+lane, row=s>>3, g=s&7;
          gload16(hbR+(size_t)row*H_+k0+((g^(row&7))*8), &As[(c+1)&1][(p*256+w*64)*8]);
        }
      }
      const ushort_t* Ac=As[c&1];
#pragma unroll
      for(int ks=0;ks<2;ks++){
        int ra=w*16+l15;
        bf16x8 a=*(const bf16x8*)&Ac[ra*64+(((ks*4+l4)^(ra&7))*8)];
#pragma unroll
        for(int n=0;n<4;n++){
          int rb=n*16+l15;
          bf16x8 b=*(const bf16x8*)&Bp[rb*H_+(((c*8+ks*4+l4)^(rb&7))*8)];
          acc[n]=__builtin_amdgcn_mfma_f32_16x16x32_bf16(a,b,acc[n],0,0,0);
        }
      }
      __syncthreads();
    }
    const int col=j0+l15;
#pragma unroll
    for(int j=0;j<4;j++){
      int row=w*16+l4*4+j;
      const float* xr=xp+(size_t)(t*64+row)*H4_;
      float g0=acc[0][j]+xr[col];
      float g1=acc[1][j]+xr[1024+col];
      float g2=acc[2][j]+xr[2048+col];
      float g3=acc[3][j]+xr[3072+col];
      size_t ix=(size_t)row*H_+col;
      float c_old=cD[ix];
      float cn=sigm(g1)*c_old+sigm(g0)*tanhf(g2);
      float hv=sigm(g3)*tanhf(cn);
      bool m=t<lens[row];
      cD[ix]= m? cn : c_old;
      hbW[ix]= m? f2bs(hv) : hbR[ix];
      outD[(size_t)(t*64+row)*H_+col]= m? f2bs(hv) : (ushort_t)0;
    }
    ep++;
    gridbar(bar, ep*(unsigned)NBE);
  }
}

// ====== persistent decoder: 47 steps x {PA gates, PB attn-alphaG, PC O-proj} ========
__global__ __launch_bounds__(256)
void dec_persist(const ushort_t* __restrict__ WoB,    // [4096][1024] bf16
                 const float* __restrict__ Yp, const float* __restrict__ whhC,
                 const float* __restrict__ dc0,
                 const ushort_t* __restrict__ encPb,  // [b*48+s][1024] bf16
                 const ushort_t* __restrict__ Gb,     // [b*48+s][1024] bf16
                 const ushort_t* __restrict__ WcombB, // [1024][3072] bf16
                 const int* __restrict__ lens,
                 ushort_t* __restrict__ opB, ushort_t* __restrict__ hB,
                 float* __restrict__ aG,              // [64][1024] fp32
                 ushort_t* __restrict__ combB,
                 unsigned* __restrict__ bar)
{
  __shared__ __align__(16) ushort_t Bp[64*1024];   // 128KB resident Wo slice
  __shared__ __align__(16) ushort_t As[2][64*64];  // 2x8KB dbuf
  __shared__ __align__(16) ushort_t Db[2][16*64];  // 2x2KB dbuf (WcH chunks)
  __shared__ float es[S_], al[S_];
  const int tid=threadIdx.x, w=tid>>6, lane=tid&63;
  const int blk=blockIdx.x, j0=blk*16, b=blk;
  const int l15=lane&15, l4=lane>>4;

  for(int p=0;p<32;p++){
    int s=p*256+w*64+lane;
    int row=s>>7, g=s&127;
    int grow=((row>>4)<<10)+j0+(row&15);
    gload16(WoB+(size_t)grow*H_+((g^(row&7))*8), &Bp[(p*256+w*64)*8]);
  }
  __syncthreads();

  unsigned ep=0;
  for(int t=0;t<T1_;t++){
    // ---------------- PA: gates = opB @ Wo^T + Yp_t + whhC; h = lstm(c0) ------------
    {
      f32x4 acc[4];
#pragma unroll
      for(int n=0;n<4;n++) acc[n]=(f32x4){0.f,0.f,0.f,0.f};
#pragma unroll 1
      for(int p=0;p<2;p++){
        int s=p*256+w*64+lane, row=s>>3, g=s&7;
        gload16(opB+(size_t)row*H_+((g^(row&7))*8), &As[0][(p*256+w*64)*8]);
      }
      __syncthreads();
      for(int c=0;c<16;c++){
        if(c<15){
          int k0=(c+1)*64;
#pragma unroll 1
          for(int p=0;p<2;p++){
            int s=p*256+w*64+lane, row=s>>3, g=s&7;
            gload16(opB+(size_t)row*H_+k0+((g^(row&7))*8), &As[(c+1)&1][(p*256+w*64)*8]);
          }
        }
        const ushort_t* Ac=As[c&1];
#pragma unroll
        for(int ks=0;ks<2;ks++){
          int ra=w*16+l15;
          bf16x8 a=*(const bf16x8*)&Ac[ra*64+(((ks*4+l4)^(ra&7))*8)];
#pragma unroll
          for(int n=0;n<4;n++){
            int rb=n*16+l15;
            bf16x8 bb=*(const bf16x8*)&Bp[rb*H_+(((c*8+ks*4+l4)^(rb&7))*8)];
            acc[n]=__builtin_amdgcn_mfma_f32_16x16x32_bf16(a,bb,acc[n],0,0,0);
          }
        }
        __syncthreads();
      }
      const int col=j0+l15;
#pragma unroll
      for(int j=0;j<4;j++){
        int row=w*16+l4*4+j;
        const float* yr=Yp+(size_t)(t*64+row)*H4_;
        const float* wr=whhC+(size_t)row*H4_;
        float g0=acc[0][j]+yr[col]     +wr[col];
        float g1=acc[1][j]+yr[1024+col]+wr[1024+col];
        float g2=acc[2][j]+yr[2048+col]+wr[2048+col];
        float g3=acc[3][j]+yr[3072+col]+wr[3072+col];
        float cn=sigm(g1)*dc0[(size_t)row*H_+col]+sigm(g0)*tanhf(g2);
        float hv=sigm(g3)*tanhf(cn);
        hB[(size_t)row*H_+col]=f2bs(hv);
      }
    }
    ep++; gridbar(bar, ep*(unsigned)NBD);

    // ---------------- PB: e_b, softmax, aG_b = alpha . G_b --------------------------
    {
      float* hs=(float*)As;                      // 4KB overlay
      {
        ushort4 hv=*(const ushort4*)(hB+(size_t)b*H_+tid*4);
        hs[tid*4+0]=b2f(hv.x); hs[tid*4+1]=b2f(hv.y);
        hs[tid*4+2]=b2f(hv.z); hs[tid*4+3]=b2f(hv.w);
      }
      __syncthreads();
      for(int s=w;s<S_;s+=4){
        const ushort_t* epr=encPb+((size_t)b*S_+s)*H_+lane*16;
        float sum=0.f;
#pragma unroll
        for(int q=0;q<2;q++){
          ushort_t tmp[8];
          *(ushort4*)&tmp[0]=*(const ushort4*)(epr+q*8);
          *(ushort4*)&tmp[4]=*(const ushort4*)(epr+q*8+4);
#pragma unroll
          for(int x=0;x<8;x++) sum+=b2f(tmp[x])*hs[lane*16+q*8+x];
        }
        for(int o=32;o>0;o>>=1) sum+=__shfl_xor(sum,o,64);
        if(lane==0) es[s]=sum;
      }
      __syncthreads();
      if(tid<64){
        int L=lens[b];
        float e=(tid<S_&&tid<L)? es[tid] : -INFINITY;
        float m=e;
        for(int o=32;o>0;o>>=1) m=fmaxf(m,__shfl_xor(m,o,64));
        float p=(tid<S_)? expf(e-m):0.f;
        float sm=p;
        for(int o=32;o>0;o>>=1) sm+=__shfl_xor(sm,o,64);
        if(tid<S_) al[tid]=p/sm;
      }
      __syncthreads();
      {
        float r0=0.f,r1=0.f,r2=0.f,r3=0.f;
        const int c4=tid*4;
        for(int s=0;s<S_;s++){
          float a=al[s];
          ushort4 g=*(const ushort4*)(Gb+((size_t)b*S_+s)*H_+c4);
          r0+=a*b2f(g.x); r1+=a*b2f(g.y); r2+=a*b2f(g.z); r3+=a*b2f(g.w);
        }
        *(float4*)(aG+(size_t)b*H_+c4)=make_float4(r0,r1,r2,r3);
      }
    }
    ep++; gridbar(bar, ep*(unsigned)NBD);

    // ---------------- PC: O = tanh(aG + hB @ WcH^T), cols j0..j0+15 -----------------
    {
      f32x4 a3=(f32x4){0.f,0.f,0.f,0.f};
#pragma unroll 1
      for(int p=0;p<2;p++){
        int s=p*256+w*64+lane, row=s>>3, g=s&7;
        gload16(hB+(size_t)row*H_+((g^(row&7))*8), &As[0][(p*256+w*64)*8]);
      }
      if(w<2){
        int s=w*64+lane, row=s>>3, g=s&7;
        gload16(WcombB+(size_t)(j0+row)*3072+2048+((g^(row&7))*8), &Db[0][(w*64)*8]);
      }
      __syncthreads();
      for(int c=0;c<16;c++){
        if(c<15){
          int k0=(c+1)*64;
#pragma unroll 1
          for(int p=0;p<2;p++){
            int s=p*256+w*64+lane, row=s>>3, g=s&7;
            gload16(hB+(size_t)row*H_+k0+((g^(row&7))*8), &As[(c+1)&1][(p*256+w*64)*8]);
          }
          if(w<2){
            int s=w*64+lane, row=s>>3, g=s&7;
            gload16(WcombB+(size_t)(j0+row)*3072+2048+k0+((g^(row&7))*8), &Db[(c+1)&1][(w*64)*8]);
          }
        }
        const ushort_t* Ac=As[c&1];
        const ushort_t* Dc=Db[c&1];
#pragma unroll
        for(int ks=0;ks<2;ks++){
          int ra=w*16+l15;
          bf16x8 a=*(const bf16x8*)&Ac[ra*64+(((ks*4+l4)^(ra&7))*8)];
          int rb=l15;
          bf16x8 bb=*(const bf16x8*)&Dc[rb*64+(((ks*4+l4)^(rb&7))*8)];
          a3=__builtin_amdgcn_mfma_f32_16x16x32_bf16(a,bb,a3,0,0,0);
        }
        __syncthreads();
      }
#pragma unroll
      for(int j=0;j<4;j++){
        int row=w*16+l4*4+j;
        float o=tanhf(a3[j]+aG[(size_t)row*H_+j0+l15]);
        opB[(size_t)row*H_+j0+l15]=f2bs(o);
        combB[((size_t)t*64+row)*H_+j0+l15]=f2bs(o);
      }
    }
    ep++; gridbar(bar, ep*(unsigned)NBD);
  }
}

// ------------------ embeddings (direct to bf16): X, Xrev, Y -------------------------
__global__ void embed_all(const int* __restrict__ src, const int* __restrict__ tgt,
                          const int* __restrict__ lens,
                          const float* __restrict__ se, const float* __restrict__ te,
                          ushort_t* __restrict__ X, ushort_t* __restrict__ Xr,
                          ushort_t* __restrict__ Y)
{
  int bi=blockIdx.x, tid=threadIdx.x;
  const float* srcrow; ushort_t* dst;
  if(bi<3072){
    int s=bi>>6, b=bi&63;
    srcrow=se+(size_t)src[s*64+b]*E_; dst=X+(size_t)bi*E_;
  } else if(bi<6144){
    int r=bi-3072, t=r>>6, b=r&63;
    int L=lens[b]; int ts=(t<L)? L-1-t : t;
    srcrow=se+(size_t)src[ts*64+b]*E_; dst=Xr+(size_t)r*E_;
  } else {
    int r=bi-6144, t=r>>6, b=r&63;
    srcrow=te+(size_t)tgt[t*64+b]*E_; dst=Y+(size_t)r*E_;
  }
  float4 v=((const float4*)srcrow)[tid];
  ushort4 o; o.x=f2bs(v.x); o.y=f2bs(v.y); o.z=f2bs(v.z); o.w=f2bs(v.w);
  ((ushort4*)dst)[tid]=o;
}

// ------------- weight conversions fp32->bf16 (all but W_voc), grid-stride -----------
__global__ void prep_w(const float* __restrict__ Whhf,const float* __restrict__ Whhb,
                       const float* __restrict__ Wihf,const float* __restrict__ Wihb,
                       const float* __restrict__ Watt,const float* __restrict__ dWih,
                       const float* __restrict__ Wcomb,
                       ushort_t* __restrict__ WhhfB,ushort_t* __restrict__ WhhbB,
                       ushort_t* __restrict__ WihfB,ushort_t* __restrict__ WihbB,
                       ushort_t* __restrict__ WattB,ushort_t* __restrict__ dWihYb,
                       ushort_t* __restrict__ dWihOb,ushort_t* __restrict__ WcombB)
{
  const int NQ=6029312;
  for(int q=blockIdx.x*256+threadIdx.x; q<NQ; q+=gridDim.x*256){
    const float* src; ushort_t* dst; size_t si,di; int r;
    if(q<1048576){ si=(size_t)q*4; src=Whhf; dst=WhhfB; di=si; }
    else if(q<2097152){ r=q-1048576; si=(size_t)r*4; src=Whhb; dst=WhhbB; di=si; }
    else if(q<2621440){ r=q-2097152; si=(size_t)r*4; src=Wihf; dst=WihfB; di=si; }
    else if(q<3145728){ r=q-2621440; si=(size_t)r*4; src=Wihb; dst=WihbB; di=si; }
    else if(q<3670016){ r=q-3145728; si=(size_t)r*4; src=Watt; dst=WattB; di=si; }
    else if(q<4194304){ r=q-3670016; int row=r>>7, c4=(r&127)*4;
                        si=(size_t)row*1536+c4; src=dWih; dst=dWihYb; di=(size_t)row*512+c4; }
    else if(q<5242880){ r=q-4194304; int row=r>>8, c4=(r&255)*4;
                        si=(size_t)row*1536+512+c4; src=dWih; dst=dWihOb; di=(size_t)row*1024+c4; }
    else { r=q-5242880; si=(size_t)r*4; src=Wcomb; dst=WcombB; di=si; }
    float4 v=*(const float4*)(src+si);
    ushort4 o; o.x=f2bs(v.x);o.y=f2bs(v.y);o.z=f2bs(v.z);o.w=f2bs(v.w);
    *(ushort4*)(dst+di)=o;
  }
}

__global__ void f2b_voc(const float* __restrict__ in, ushort_t* __restrict__ out){
  for(size_t q=blockIdx.x*256+threadIdx.x; q<8192000; q+=(size_t)gridDim.x*256){
    float4 v=*(const float4*)(in+q*4);
    ushort4 o; o.x=f2bs(v.x);o.y=f2bs(v.y);o.z=f2bs(v.z);o.w=f2bs(v.w);
    *(ushort4*)(out+q*4)=o;
  }
}

// --- build enc_hiddens bf16 with bwd un-reversal; concat final h/c (fp32) -----------
__global__ void gather_concat(const ushort_t* __restrict__ outF, const ushort_t* __restrict__ outBR,
                              const int* __restrict__ lens,
                              const ushort_t* __restrict__ hb, const float* __restrict__ cst,
                              ushort_t* __restrict__ encHb,
                              float* __restrict__ hcat, float* __restrict__ ccat)
{
  int bi=blockIdx.x, tid=threadIdx.x;
  if(bi<3072){
    int b=bi/48, s=bi%48;
    int L=lens[b]; int sr=(s<L)? L-1-s : s;
    ((ushort4*)(encHb+(size_t)bi*2048))[tid]      =((const ushort4*)(outF +(size_t)(s*64+b)*H_))[tid];
    ((ushort4*)(encHb+(size_t)bi*2048+1024))[tid] =((const ushort4*)(outBR+(size_t)(sr*64+b)*H_))[tid];
  } else {
    int b=bi-3072;
    for(int i=tid;i<H_;i+=256){
      hcat[(size_t)b*2048+i]      = b2f(hb[(size_t)b*H_+i]);
      hcat[(size_t)b*2048+1024+i] = b2f(hb[65536+(size_t)b*H_+i]);
      ccat[(size_t)b*2048+i]      = cst[(size_t)b*H_+i];
      ccat[(size_t)b*2048+1024+i] = cst[65536+(size_t)b*H_+i];
    }
  }
}

// ---------------- fp32 NT GEMM (small: dh0/dc0/whhC) --------------------------------
template<int BM,int BN,int TM,int TN>
__global__ __launch_bounds__(256)
void gemm_nt(int M, int K,
             const float* __restrict__ A, int lda,
             const float* __restrict__ B, int ldb,
             float* __restrict__ C, int ldc,
             const float* __restrict__ bias)
{
  constexpr int BK=16;
  __shared__ float As[BK][BM+4];
  __shared__ float Bs[BK][BN+4];
  const int tid=threadIdx.x;
  constexpr int TX=BN/TN;
  const int tx=tid%TX, ty=tid/TX;
  const int m0=blockIdx.x*BM, n0=blockIdx.y*BN;
  float acc[TM][TN];
#pragma unroll
  for(int i=0;i<TM;i++)
#pragma unroll
    for(int j=0;j<TN;j++) acc[i][j]=0.f;
  for(int k0=0;k0<K;k0+=BK){
    for(int i=tid;i<BM*4;i+=256){
      int r=i>>2, c=(i&3)*4;
      float4 v=make_float4(0.f,0.f,0.f,0.f);
      if(m0+r<M) v=*(const float4*)(A+(size_t)(m0+r)*lda+k0+c);
      As[c+0][r]=v.x; As[c+1][r]=v.y; As[c+2][r]=v.z; As[c+3][r]=v.w;
    }
    for(int i=tid;i<BN*4;i+=256){
      int r=i>>2, c=(i&3)*4;
      float4 v=*(const float4*)(B+(size_t)(n0+r)*ldb+k0+c);
      Bs[c+0][r]=v.x; Bs[c+1][r]=v.y; Bs[c+2][r]=v.z; Bs[c+3][r]=v.w;
    }
    __syncthreads();
#pragma unroll
    for(int k=0;k<BK;k++){
      float a[TM], bb[TN];
#pragma unroll
      for(int i=0;i<TM;i++) a[i]=As[k][ty*TM+i];
#pragma unroll
      for(int j=0;j<TN;j++) bb[j]=Bs[k][tx*TN+j];
#pragma unroll
      for(int i=0;i<TM;i++)
#pragma unroll
        for(int j=0;j<TN;j++) acc[i][j]+=a[i]*bb[j];
    }
    __syncthreads();
  }
#pragma unroll
  for(int i=0;i<TM;i++){
    int r=m0+ty*TM+i;
    if(r>=M) continue;
#pragma unroll
    for(int j=0;j<TN;j++){
      int c=n0+tx*TN+j;
      float v=acc[i][j];
      if(bias) v+=bias[c];
      C[(size_t)r*ldc+c]=v;
    }
  }
}

__global__ __launch_bounds__(256)
void lse_final(const float* __restrict__ pmax, const float* __restrict__ psum,
               const float* __restrict__ gold, float* __restrict__ gl)
{
  __shared__ float red[256];
  const int r=blockIdx.x, tid=threadIdx.x;
  float m=-INFINITY;
  for(int i=tid;i<NTV_;i+=256) m=fmaxf(m,pmax[(size_t)r*NTV_+i]);
  red[tid]=m; __syncthreads();
  for(int k=128;k>0;k>>=1){ if(tid<k) red[tid]=fmaxf(red[tid],red[tid+k]); __syncthreads(); }
  float M=red[0]; __syncthreads();
  float s=0.f;
  for(int i=tid;i<NTV_;i+=256) s+=psum[(size_t)r*NTV_+i]*expf(pmax[(size_t)r*NTV_+i]-M);
  red[tid]=s; __syncthreads();
  for(int k=128;k>0;k>>=1){ if(tid<k) red[tid]+=red[tid+k]; __syncthreads(); }
  if(tid==0) gl[r]=gold[r]-(M+logf(red[0]));
}

__global__ void final_sum(const float* __restrict__ gl, const int* __restrict__ tgt,
                          float* __restrict__ out)
{
  int b=threadIdx.x;
  float acc=0.f;
  for(int t=0;t<T1_;t++){
    int tk=tgt[(t+1)*B_+b];
    if(tk!=0) acc+=gl[t*B_+b];
  }
  out[b]=acc;
}

// =====================================================================================
extern "C" void kernel_launch(void* const* d_in, const int* in_sizes, int n_in,
                              void* d_out, int out_size, void* d_ws, size_t ws_size,
                              hipStream_t stream)
{
  (void)in_sizes; (void)n_in; (void)out_size; (void)ws_size;
  const int*   src    =(const int*)  d_in[0];
  const int*   tgt    =(const int*)  d_in[1];
  const int*   lens   =(const int*)  d_in[2];
  const float* src_emb=(const float*)d_in[3];
  const float* tgt_emb=(const float*)d_in[4];
  const float* Wih_f  =(const float*)d_in[5];
  const float* Whh_f  =(const float*)d_in[6];
  const float* b_f    =(const float*)d_in[7];
  const float* Wih_b  =(const float*)d_in[8];
  const float* Whh_b  =(const float*)d_in[9];
  const float* b_b    =(const float*)d_in[10];
  const float* dWih   =(const float*)d_in[11];
  const float* dWhh   =(const float*)d_in[12];
  const float* db     =(const float*)d_in[13];
  const float* W_h    =(const float*)d_in[14];
  const float* W_c    =(const float*)d_in[15];
  const float* W_att  =(const float*)d_in[16];
  const float* W_comb =(const float*)d_in[17];
  const float* W_voc  =(const float*)d_in[18];
  float* out=(float*)d_out;
  float* W  =(float*)d_ws;

  size_t off=0;
  auto AL=[&](size_t n){ size_t o=off; off+=n; return o; };
  // ---- fp32 region ----
  const size_t oXpF  =AL((size_t)3072*H4_);   // dead after encoder -> WvocB, G, LSE bufs
  const size_t oXpB  =AL((size_t)3072*H4_);
  const size_t oYp   =AL((size_t)3072*H4_);
  const size_t oCst  =AL((size_t)2*64*H_);
  const size_t oHcat =AL((size_t)64*2048);
  const size_t oCcat =AL((size_t)64*2048);
  const size_t oDh0  =AL((size_t)64*H_);
  const size_t oDc0  =AL((size_t)64*H_);
  const size_t oWhhC =AL((size_t)64*H4_);
  const size_t oAG   =AL((size_t)64*H_);
  const size_t oBar  =AL((size_t)64);
  // ---- bf16 region (ushort counts / 2) ----
  const size_t oXb    =AL((size_t)3072*E_/2);
  const size_t oXrb   =AL((size_t)3072*E_/2);
  const size_t oYb    =AL((size_t)3072*E_/2);
  const size_t oWhhfB =AL((size_t)H4_*H_/2);
  const size_t oWhhbB =AL((size_t)H4_*H_/2);
  const size_t oWihfB =AL((size_t)H4_*E_/2);
  const size_t oWihbB =AL((size_t)H4_*E_/2);
  const size_t oWattB =AL((size_t)H_*2048/2);
  const size_t odWihYb=AL((size_t)H4_*E_/2);
  const size_t odWihOb=AL((size_t)H4_*H_/2);
  const size_t oWcombB=AL((size_t)H_*3072/2);
  const size_t oHbuf  =AL((size_t)2*2*64*H_/2);
  const size_t oOutF  =AL((size_t)S_*64*H_/2);    // alias: combB in decoder
  const size_t oOutBR =AL((size_t)S_*64*H_/2);
  const size_t oEncHb =AL((size_t)3072*2048/2);
  const size_t oEncPb =AL((size_t)3072*H_/2);
  const size_t oHB    =AL((size_t)64*H_/2);
  const size_t oOpB   =AL((size_t)64*H_/2);

  ushort_t* Xb    =(ushort_t*)(W+oXb);
  ushort_t* Xrb   =(ushort_t*)(W+oXrb);
  ushort_t* Yb    =(ushort_t*)(W+oYb);
  ushort_t* WhhfB =(ushort_t*)(W+oWhhfB);
  ushort_t* WihfB =(ushort_t*)(W+oWihfB);
  ushort_t* WihbB =(ushort_t*)(W+oWihbB);
  ushort_t* WattB =(ushort_t*)(W+oWattB);
  ushort_t* dWihYb=(ushort_t*)(W+odWihYb);
  ushort_t* dWihOb=(ushort_t*)(W+odWihOb);
  ushort_t* WcombB=(ushort_t*)(W+oWcombB);
  ushort_t* Hbuf  =(ushort_t*)(W+oHbuf);
  ushort_t* OutF  =(ushort_t*)(W+oOutF);
  ushort_t* OutBR =(ushort_t*)(W+oOutBR);
  ushort_t* EncHb =(ushort_t*)(W+oEncHb);
  ushort_t* EncPb =(ushort_t*)(W+oEncPb);
  ushort_t* HB    =(ushort_t*)(W+oHB);
  ushort_t* OpB   =(ushort_t*)(W+oOpB);
  // aliases in dead XpF/XpB region (dead after encoder):
  ushort_t* WvocB =(ushort_t*)(W+oXpF);                   // 8.19M floats
  ushort_t* Gbuf  =(ushort_t*)(W+oXpF+8400000);           // 1.54M floats
  float* pmax = W+oXpF+16500000;                          // in oXpB region
  float* psum = pmax+ (size_t)NROW_*NTV_;
  float* gold = psum+ (size_t)NROW_*NTV_;
  float* gl   = gold+ NROW_;
  ushort_t* CombB =(ushort_t*)(W+oOutF);
  unsigned* bar0=(unsigned*)(W+oBar);
  unsigned* bar1=bar0+16;

  // ---- per-call init (re-zeroed on every replay) ----
  hipMemsetAsync(W+oBar, 0, 64*sizeof(float), stream);
  hipMemsetAsync(W+oCst, 0, (size_t)2*64*H_*sizeof(float), stream);
  hipMemsetAsync(Hbuf,   0, (size_t)2*2*64*H_*sizeof(ushort_t), stream);
  hipMemsetAsync(OpB,    0, (size_t)64*H_*sizeof(ushort_t), stream);

  // ---- prep ----
  embed_all<<<dim3(3072+3072+NROW_),128,0,stream>>>(src,tgt,lens,src_emb,tgt_emb,Xb,Xrb,Yb);
  prep_w<<<dim3(2048),256,0,stream>>>(Whh_f,Whh_b,Wih_f,Wih_b,W_att,dWih,W_comb,
                                      WhhfB,(ushort_t*)(W+oWhhbB),WihfB,WihbB,WattB,
                                      dWihYb,dWihOb,WcombB);
  proj3<<<dim3(24,32,3),256,0,stream>>>(Xb,WihfB,b_f, Xrb,WihbB,b_b, Yb,dWihYb,
                                        W+oXpF,W+oXpB,W+oYp);

  // ---- encoder (1 launch, 48 steps) ----
  enc_persist<<<dim3(NBE),256,0,stream>>>(WhhfB, W+oXpF, W+oXpB, lens,
                                          Hbuf, W+oCst, OutF, OutBR, bar0);

  // ---- mid section ----
  gather_concat<<<dim3(3136),256,0,stream>>>(OutF,OutBR,lens,Hbuf,W+oCst,
                                             EncHb,W+oHcat,W+oCcat);
  f2b_voc<<<dim3(2048),256,0,stream>>>(W_voc, WvocB);
  bproj<<<dim3(24,8),256,0,stream>>>(EncHb,2048, WattB,2048, 2048, EncPb);   // enc_proj
  bproj<<<dim3(24,8),256,0,stream>>>(EncHb,2048, WcombB,3072, 2048, Gbuf);   // G = encH @ WcA^T
  gemm_nt<64,64,4,4><<<dim3(1,16),256,0,stream>>>(64,2048, W+oHcat,2048, W_h,2048, W+oDh0,H_, nullptr);
  gemm_nt<64,64,4,4><<<dim3(1,16),256,0,stream>>>(64,2048, W+oCcat,2048, W_c,2048, W+oDc0,H_, nullptr);
  gemm_nt<64,64,4,4><<<dim3(1,64),256,0,stream>>>(64,H_, W+oDh0,H_, dWhh,H_, W+oWhhC,H4_, db);

  // ---- decoder (1 launch, 47 steps x 3 phases) ----
  dec_persist<<<dim3(NBD),256,0,stream>>>(dWihOb, W+oYp, W+oWhhC, W+oDc0,
                                          EncPb, Gbuf, WcombB, lens,
                                          OpB, HB, W+oAG, CombB, bar1);

  // ---- vocab + LSE + output ----
  mfma_vocab<<<dim3(24,NTV_/2),256,0,stream>>>(CombB, WvocB, tgt, pmax, psum, gold);
  lse_final<<<dim3(NROW_),256,0,stream>>>(pmax, psum, gold, gl);
  final_sum<<<dim3(1),64,0,stream>>>(gl, tgt, out);
}